// Round 8
// baseline (797.514 us; speedup 1.0000x reference)
//
#include <hip/hip_runtime.h>
#include <hip/hip_bf16.h>

#define E_TOTAL   800000
#define NN        50000
#define DD        128
#define DE        64
#define ZDIM      320
#define MT        64
#define SB        16       // sumb rows kept in LDS (overflow -> global atomics)
#define NBS       196      // scan blocks: 196*256 = 50176 >= NN

typedef short bf16x8 __attribute__((ext_vector_type(8)));
typedef float f32x4  __attribute__((ext_vector_type(4)));

__device__ __forceinline__ unsigned short f2bf(float f) {
    union { float f; unsigned int u; } v; v.f = f;
    unsigned int u = v.u;
    return (unsigned short)((u + 0x7fffu + ((u >> 16) & 1u)) >> 16);
}

__device__ __forceinline__ float bf2f(unsigned short h) {
    union { unsigned u; float f; } v; v.u = ((unsigned)h) << 16; return v.f;
}

__device__ __forceinline__ unsigned pkbf2(float a, float b) {
    __hip_bfloat162 h = __float22bfloat162_rn(make_float2(a, b));
    unsigned u; __builtin_memcpy(&u, &h, 4); return u;
}

__device__ __forceinline__ uint2 pkbf4(float4 v) {
    uint2 r; r.x = pkbf2(v.x, v.y); r.y = pkbf2(v.z, v.w); return r;
}

__device__ __forceinline__ float fast_rcp(float x) {
#if __has_builtin(__builtin_amdgcn_rcpf)
    return __builtin_amdgcn_rcpf(x);
#else
    return 1.0f / x;
#endif
}

// ===================== sorting helpers =====================

__global__ void scan_part(const int* __restrict__ counts, int* __restrict__ partial) {
    __shared__ int red[256];
    int t = threadIdx.x, k = blockIdx.x * 256 + t;
    red[t] = (k < NN) ? counts[k] : 0;
    __syncthreads();
    for (int d = 128; d > 0; d >>= 1) {
        if (t < d) red[t] += red[t + d];
        __syncthreads();
    }
    if (t == 0) partial[blockIdx.x] = red[0];
}

__global__ void scan_top(int* __restrict__ partial) {
    __shared__ int s[256];
    int t = threadIdx.x;
    int v = (t < NBS) ? partial[t] : 0;
    s[t] = v; __syncthreads();
    for (int d = 1; d < 256; d <<= 1) {
        int a = (t >= d) ? s[t - d] : 0;
        __syncthreads();
        s[t] += a;
        __syncthreads();
    }
    if (t < NBS) partial[t] = s[t] - v;
}

__global__ void scan_final(const int* __restrict__ counts,
                           const int* __restrict__ partial,
                           int* __restrict__ cursor) {
    __shared__ int s[256];
    int t = threadIdx.x, k = blockIdx.x * 256 + t;
    int v = (k < NN) ? counts[k] : 0;
    s[t] = v; __syncthreads();
    for (int d = 1; d < 256; d <<= 1) {
        int a = (t >= d) ? s[t - d] : 0;
        __syncthreads();
        s[t] += a;
        __syncthreads();
    }
    if (k < NN) cursor[k] = partial[blockIdx.x] + s[t] - v;
}

// scan_top folded in — each block prefix-sums the 196 partials itself.
__global__ void scan_final2(const int* __restrict__ counts,
                            const int* __restrict__ partial,
                            int* __restrict__ cursor) {
    __shared__ int s[256], p2[256], orig[256];
    int t = threadIdx.x, k = blockIdx.x * 256 + t;
    int pv = (t < NBS) ? partial[t] : 0;
    p2[t] = pv; orig[t] = pv; __syncthreads();
    for (int d = 1; d < 256; d <<= 1) {
        int a = (t >= d) ? p2[t - d] : 0;
        __syncthreads();
        p2[t] += a;
        __syncthreads();
    }
    int blkoff = p2[blockIdx.x] - orig[blockIdx.x];
    int v = (k < NN) ? counts[k] : 0;
    s[t] = v; __syncthreads();
    for (int d = 1; d < 256; d <<= 1) {
        int a = (t >= d) ? s[t - d] : 0;
        __syncthreads();
        s[t] += a;
        __syncthreads();
    }
    if (k < NN) cursor[k] = blkoff + s[t] - v;
}

// spak2[pos] = { (dst<<16)|src , eid }
__global__ void scatter_kernel(const int* __restrict__ ei, int* __restrict__ cursor,
                               uint2* __restrict__ spak2) {
    int e = blockIdx.x * 256 + threadIdx.x;
    if (e < E_TOTAL) {
        int d = ei[E_TOTAL + e];
        int pos = atomicAdd(&cursor[d], 1);
        uint2 p; p.x = ((unsigned)d << 16) | (unsigned)ei[e]; p.y = (unsigned)e;
        spak2[pos] = p;
    }
}

// ===================== main-path prep =====================

// aggr <- 0 ; hist(dst) ; WtE[n][k]=W[256+k][n'] ; WtN[part][n][k]=W[part*128+k][n']
__global__ void prep_kernel4(const int* __restrict__ ei,
                             const float* __restrict__ W_f,
                             const float* __restrict__ W_s,
                             unsigned short* __restrict__ WtE,
                             unsigned short* __restrict__ WtN,
                             int* __restrict__ counts,
                             float* __restrict__ aggr) {
    int id = blockIdx.x * 256 + threadIdx.x;          // grid = NN*DD/4 exactly
    float4 z; z.x = 0.f; z.y = 0.f; z.z = 0.f; z.w = 0.f;
    ((float4*)aggr)[id] = z;
    if (id < E_TOTAL) atomicAdd(&counts[ei[E_TOTAL + id]], 1);
    if (id < 256 * DE) {
        int n = id >> 6, k = id & 63;
        int ok = 2 * DD + k;
        float wv = (n < DD) ? W_f[ok * DD + n] : W_s[ok * DD + (n - DD)];
        WtE[id] = f2bf(wv);
    } else if (id < 256 * DE + 2 * 256 * DD) {
        int id2 = id - 256 * DE;
        int part = id2 >> 15;
        int r = id2 & 32767;
        int n = r >> 7, k = r & 127;
        int ok = part * DD + k;
        float wv = (n < DD) ? W_f[ok * DD + n] : W_s[ok * DD + (n - DD)];
        WtN[id2] = f2bf(wv);
    }
}

// nodeP32[node*256 + part*128 + c] = pkbf2(f_c, s_c); part0=dst(+bias), part1=src.
// Both projections in ONE 512-thread block sharing a single x-tile staging.
__global__ __launch_bounds__(512, 4)
void node_kernel3(const float* __restrict__ x,
                  const unsigned short* __restrict__ WtN,
                  const float* __restrict__ bf_, const float* __restrict__ bs_,
                  unsigned int* __restrict__ nodeP32) {
    __shared__ unsigned short A_lds[MT * DD];  // 16 KB
    const int t = threadIdx.x;
    const int m_off = blockIdx.x * MT;
    const int lane = t & 63, w8 = t >> 6;
    const int part = w8 >> 2, w = w8 & 3;
    const int l15 = lane & 15, quad = lane >> 4;

    #pragma unroll
    for (int it = 0; it < 4; ++it) {
        int idx = it * 512 + t;
        int e = idx >> 5, kq = idx & 31;
        int row = m_off + e; if (row >= NN) row = NN - 1;
        float4 v = ((const float4*)(x + (size_t)row * DD))[kq];
        int g = kq >> 1;
        int col = ((g & ~7) | ((g & 7) ^ (e & 7))) * 8 + (kq & 1) * 4;
        *((uint2*)&A_lds[e * DD + col]) = pkbf4(v);
    }

    f32x4 acc[4][4] = {};
    const int nt0 = 2 * w;
    const unsigned short* Bp[4];
    #pragma unroll
    for (int u = 0; u < 4; ++u) {
        int nt = nt0 + ((u < 2) ? u : (6 + u));
        Bp[u] = WtN + (size_t)part * (256 * DD) +
                (size_t)(nt * 16 + l15) * DD + quad * 8;
    }
    __syncthreads();

    #pragma unroll
    for (int ks = 0; ks < 4; ++ks) {
        bf16x8 af[4], bfr[4];
        #pragma unroll
        for (int i = 0; i < 4; ++i) {
            int m = i * 16 + l15;
            int g = 4 * ks + quad;
            int col = ((g & ~7) | ((g & 7) ^ (l15 & 7))) * 8;
            af[i] = *((const bf16x8*)&A_lds[m * DD + col]);
        }
        #pragma unroll
        for (int u = 0; u < 4; ++u)
            bfr[u] = *((const bf16x8*)(Bp[u] + ks * 32));
        #pragma unroll
        for (int i = 0; i < 4; ++i)
            #pragma unroll
            for (int u = 0; u < 4; ++u)
                acc[i][u] = __builtin_amdgcn_mfma_f32_16x16x32_bf16(
                    af[i], bfr[u], acc[i][u], 0, 0, 0);
    }

    const int c0 = 32 * w + l15, c1 = c0 + 16;
    const float bf0 = part ? 0.f : bf_[c0], bs0 = part ? 0.f : bs_[c0];
    const float bf1 = part ? 0.f : bf_[c1], bs1 = part ? 0.f : bs_[c1];
    #pragma unroll
    for (int i = 0; i < 4; ++i)
        #pragma unroll
        for (int j = 0; j < 4; ++j) {
            int e = i * 16 + quad * 4 + j;
            int row = m_off + e;
            if (row < NN) {
                unsigned int* np = nodeP32 + (size_t)row * 256 + part * 128;
                np[c0] = pkbf2(acc[i][0][j] + bf0, acc[i][2][j] + bs0);
                np[c1] = pkbf2(acc[i][1][j] + bf1, acc[i][3][j] + bs1);
            }
        }
}

// ===================== main edge kernel (R8: small sumb -> 4 blocks/CU) =====
// R7 structure unchanged EXCEPT sumb shrinks 64->16 rows (32->8 KB LDS):
// runs with rid >= SB (statistically near-never at avg degree 16, always
// correct) bypass LDS and atomicAdd straight into zero-init aggr.
// LDS 43 -> ~18 KB: 4 blocks/CU (thread-capped), theoretical occupancy 100%.
// __launch_bounds__(512,8): 64-reg budget (was 52) — MUST NOT spill.
__global__ __launch_bounds__(512, 8)
void edge_kernel6(const float* __restrict__ ea,
                  const unsigned short* __restrict__ WtE,
                  const unsigned int* __restrict__ nodeP32,
                  float* __restrict__ aggr,
                  const uint2* __restrict__ spak2) {
    __shared__ float sumb[SB][DD];              // 8 KB run-sum buffer
    __shared__ unsigned short A_lds[MT * DE];   // 8192 B
    __shared__ int dst_lds[MT];
    __shared__ int src_lds[MT];
    __shared__ int eid_lds[MT];
    __shared__ int runid_lds[MT];
    __shared__ int rdst_lds[MT];
    __shared__ int rbound_lds[MT];
    __shared__ int ndist_lds;

    const int t = threadIdx.x;
    const int m_off = blockIdx.x * MT;
    const int lane = t & 63, w2 = t >> 6, l15 = lane & 15, quad = lane >> 4;

    if (t < MT) {                               // wave 0 exactly
        uint2 p = spak2[m_off + t];
        int dsv = (int)(p.x >> 16);
        dst_lds[t] = dsv;
        src_lds[t] = (int)(p.x & 0xffffu);
        eid_lds[t] = (int)p.y;
        int updsv = __shfl_up(dsv, 1);
        int flag = (t == 0 || dsv != updsv) ? 1 : 0;
        unsigned long long m = __ballot(flag != 0);
        int rid = __popcll(m << (63 - t)) - 1;  // inclusive-scan(flag) - 1
        runid_lds[t] = rid;
        if (flag) { rdst_lds[rid] = dsv; rbound_lds[rid] = 0; }
        int nd = __popcll(m);
        if (t == 0) {
            ndist_lds = nd;
            if (m_off > 0 && (int)(spak2[m_off - 1].x >> 16) == dsv)
                rbound_lds[0] = 1;              // run 0 continues prev block
        }
        if (t == MT - 1) {
            if (m_off + MT < E_TOTAL &&
                (int)(spak2[m_off + MT].x >> 16) == dsv)
                rbound_lds[nd - 1] = 1;         // last run continues next block
        }
    }
    __syncthreads();

    const int c = 16 * w2 + l15;                 // this thread's output col

    // 1) ea loads first (oldest in vm queue -> staging wait is cheap)
    float4 va[2];
    #pragma unroll
    for (int it = 0; it < 2; ++it) {
        int idx = it * 512 + t;
        int e = idx >> 4;
        va[it] = ((const float4*)(ea + (size_t)eid_lds[e] * DE))[idx & 15];
    }
    // 2) prefetch all epilogue gathers (consumed after the GEMM)
    unsigned int ps[16], pd[16];
    #pragma unroll
    for (int i = 0; i < 4; ++i)
        #pragma unroll
        for (int j = 0; j < 4; ++j) {
            int e = i * 16 + quad * 4 + j;
            ps[i * 4 + j] = nodeP32[(size_t)src_lds[e] * 256 + 128 + c];
            pd[i * 4 + j] = nodeP32[(size_t)dst_lds[e] * 256 + c];
        }
    // 2b) zero sumb (SB*DD = 2048 = 4 per thread)
    {
        int col = t & 127;
        #pragma unroll
        for (int r = t >> 7; r < SB; r += 4) sumb[r][col] = 0.f;
    }
    // 3) cvt + LDS store of ea -> cols [0,64)
    #pragma unroll
    for (int it = 0; it < 2; ++it) {
        int idx = it * 512 + t;
        int e = idx >> 4, kq = idx & 15;
        int g = kq >> 1;                              // 0..7
        int col = ((g & 7) ^ (e & 7)) * 8 + (kq & 1) * 4;
        *((uint2*)&A_lds[e * DE + col]) = pkbf4(va[it]);
    }

    f32x4 acc[4][2] = {};
    const unsigned short* Bp[2];
    #pragma unroll
    for (int u = 0; u < 2; ++u) {
        int nt = w2 + u * 8;                      // u0: f-cols, u1: s-cols
        Bp[u] = WtE + (size_t)(nt * 16 + l15) * DE + quad * 8;
    }
    __syncthreads();

    #pragma unroll
    for (int ks = 0; ks < 2; ++ks) {
        bf16x8 af[4], bfr[2];
        #pragma unroll
        for (int i = 0; i < 4; ++i) {
            int m = i * 16 + l15;
            int g = 4 * ks + quad;                    // 0..7
            int col = ((g & 7) ^ (l15 & 7)) * 8;
            af[i] = *((const bf16x8*)&A_lds[m * DE + col]);
        }
        #pragma unroll
        for (int u = 0; u < 2; ++u)
            bfr[u] = *((const bf16x8*)(Bp[u] + ks * 32));
        #pragma unroll
        for (int i = 0; i < 4; ++i)
            #pragma unroll
            for (int u = 0; u < 2; ++u)
                acc[i][u] = __builtin_amdgcn_mfma_f32_16x16x32_bf16(
                    af[i], bfr[u], acc[i][u], 0, 0, 0);
    }

    int rprev = -1, dprev = -1;
    float s0 = 0.f, nf = 0.f, ns = 0.f;
    #pragma unroll
    for (int i = 0; i < 4; ++i)
        #pragma unroll
        for (int j = 0; j < 4; ++j) {
            int e = i * 16 + quad * 4 + j;
            int rid = runid_lds[e];
            if (rid != rprev) {
                if (rprev >= 0) {
                    if (rprev < SB) atomicAdd(&sumb[rprev][c], s0);
                    else atomicAdd(aggr + (size_t)dprev * DD + c, s0);
                }
                rprev = rid; s0 = 0.f;
                dprev = dst_lds[e];
                unsigned int pk = pd[i * 4 + j];
                nf = bf2f((unsigned short)(pk & 0xffffu));
                ns = bf2f((unsigned short)(pk >> 16));
            }
            unsigned int pp = ps[i * 4 + j];
            float f  = acc[i][0][j] + nf + bf2f((unsigned short)(pp & 0xffffu));
            float sg = acc[i][1][j] + ns + bf2f((unsigned short)(pp >> 16));
            s0 += fast_rcp(1.f + __expf(-f)) *
                  (fmaxf(sg, 0.f) + __logf(1.f + __expf(-fabsf(sg))));
        }
    if (rprev < SB) atomicAdd(&sumb[rprev][c], s0);
    else atomicAdd(aggr + (size_t)dprev * DD + c, s0);
    __syncthreads();

    // write-out: one op per (run, col). Interior run => single-writer STORE.
    {
        int nd = ndist_lds; if (nd > SB) nd = SB;
        int col = t & 127, rb = t >> 7;
        for (int r = rb; r < nd; r += 4) {
            float v = sumb[r][col];
            float* op = aggr + (size_t)rdst_lds[r] * DD + col;
            if (rbound_lds[r]) atomicAdd(op, v);
            else *op = v;
        }
    }
}

// out = relu(x + aggr)
__global__ void relu_kernel4(const float* __restrict__ x,
                             const float* __restrict__ aggr,
                             float* __restrict__ out) {
    int id = blockIdx.x * 256 + threadIdx.x;
    if (id < NN * DD / 4) {
        float4 xv = ((const float4*)x)[id];
        float4 av = ((const float4*)aggr)[id];
        float4 v;
        v.x = fmaxf(xv.x + av.x, 0.0f); v.y = fmaxf(xv.y + av.y, 0.0f);
        v.z = fmaxf(xv.z + av.z, 0.0f); v.w = fmaxf(xv.w + av.w, 0.0f);
        ((float4*)out)[id] = v;
    }
}

// ===================== path2 fallback (R4 exact) =====================

__global__ void prep_kernel2(const float* __restrict__ x,
                             const int* __restrict__ ei,
                             const float* __restrict__ W_f,
                             const float* __restrict__ W_s,
                             unsigned short* __restrict__ WtE,
                             unsigned short* __restrict__ WtN,
                             int* __restrict__ counts,
                             float* __restrict__ out) {
    int id = blockIdx.x * 256 + threadIdx.x;
    ((float4*)out)[id] = ((const float4*)x)[id];
    if (id < E_TOTAL) atomicAdd(&counts[ei[E_TOTAL + id]], 1);
    if (id < 256 * DE) {
        int n = id >> 6, k = id & 63;
        int ok = 2 * DD + k;
        float wv = (n < DD) ? W_f[ok * DD + n] : W_s[ok * DD + (n - DD)];
        WtE[id] = f2bf(wv);
    } else if (id < 256 * DE + 2 * 256 * DD) {
        int id2 = id - 256 * DE;
        int part = id2 >> 15;
        int r = id2 & 32767;
        int n = r >> 7, k = r & 127;
        int ok = part * DD + k;
        float wv = (n < DD) ? W_f[ok * DD + n] : W_s[ok * DD + (n - DD)];
        WtN[id2] = f2bf(wv);
    }
}

__global__ __launch_bounds__(256, 4)
void node_kernel2(const float* __restrict__ x,
                  const unsigned short* __restrict__ WtN,
                  const float* __restrict__ bf_, const float* __restrict__ bs_,
                  unsigned int* __restrict__ nodeP32) {
    __shared__ unsigned short A_lds[MT * DD];
    const int t = threadIdx.x;
    const int m_off = blockIdx.x * MT;
    const int part = blockIdx.y;
    const int lane = t & 63, w = t >> 6, l15 = lane & 15, quad = lane >> 4;

    #pragma unroll
    for (int it = 0; it < 8; ++it) {
        int idx = it * 256 + t;
        int e = idx >> 5, kq = idx & 31;
        int row = m_off + e; if (row >= NN) row = NN - 1;
        float4 v = ((const float4*)(x + (size_t)row * DD))[kq];
        int g = kq >> 1;
        int col = ((g & ~7) | ((g & 7) ^ (e & 7))) * 8 + (kq & 1) * 4;
        *((uint2*)&A_lds[e * DD + col]) = pkbf4(v);
    }

    f32x4 acc[4][4] = {};
    const int nt0 = 2 * w;
    const unsigned short* Bp[4];
    #pragma unroll
    for (int u = 0; u < 4; ++u) {
        int nt = nt0 + ((u < 2) ? u : (6 + u));
        Bp[u] = WtN + (size_t)part * (256 * DD) +
                (size_t)(nt * 16 + l15) * DD + quad * 8;
    }
    __syncthreads();

    #pragma unroll
    for (int ks = 0; ks < 4; ++ks) {
        bf16x8 af[4], bfr[4];
        #pragma unroll
        for (int i = 0; i < 4; ++i) {
            int m = i * 16 + l15;
            int g = 4 * ks + quad;
            int col = ((g & ~7) | ((g & 7) ^ (l15 & 7))) * 8;
            af[i] = *((const bf16x8*)&A_lds[m * DD + col]);
        }
        #pragma unroll
        for (int u = 0; u < 4; ++u)
            bfr[u] = *((const bf16x8*)(Bp[u] + ks * 32));
        #pragma unroll
        for (int i = 0; i < 4; ++i)
            #pragma unroll
            for (int u = 0; u < 4; ++u)
                acc[i][u] = __builtin_amdgcn_mfma_f32_16x16x32_bf16(
                    af[i], bfr[u], acc[i][u], 0, 0, 0);
    }

    const int c0 = 32 * w + l15, c1 = c0 + 16;
    const float bf0 = part ? 0.f : bf_[c0], bs0 = part ? 0.f : bs_[c0];
    const float bf1 = part ? 0.f : bf_[c1], bs1 = part ? 0.f : bs_[c1];
    #pragma unroll
    for (int i = 0; i < 4; ++i)
        #pragma unroll
        for (int j = 0; j < 4; ++j) {
            int e = i * 16 + quad * 4 + j;
            int row = m_off + e;
            if (row < NN) {
                unsigned int* np = nodeP32 + (size_t)row * 256 + part * 128;
                np[c0] = pkbf2(acc[i][0][j] + bf0, acc[i][2][j] + bs0);
                np[c1] = pkbf2(acc[i][1][j] + bf1, acc[i][3][j] + bs1);
            }
        }
}

__global__ __launch_bounds__(512, 4)
void edge_kernel2(const float* __restrict__ ea,
                  const unsigned short* __restrict__ WtE,
                  const unsigned int* __restrict__ nodeP32,
                  float* __restrict__ out,
                  const uint2* __restrict__ spak2) {
    __shared__ float sumb[MT][DD];
    __shared__ unsigned short A_lds[MT * DE];
    __shared__ int dst_lds[MT];
    __shared__ int src_lds[MT];
    __shared__ int eid_lds[MT];
    __shared__ int runid_lds[MT];
    __shared__ int rdst_lds[MT];
    __shared__ int rbound_lds[MT];
    __shared__ int ndist_lds;

    const int t = threadIdx.x;
    const int m_off = blockIdx.x * MT;
    const int lane = t & 63, w2 = t >> 6, l15 = lane & 15, quad = lane >> 4;

    if (t < MT) {
        uint2 p = spak2[m_off + t];
        int dsv = (int)(p.x >> 16);
        dst_lds[t] = dsv;
        src_lds[t] = (int)(p.x & 0xffffu);
        eid_lds[t] = (int)p.y;
        int updsv = __shfl_up(dsv, 1);
        int flag = (t == 0 || dsv != updsv) ? 1 : 0;
        unsigned long long m = __ballot(flag != 0);
        int rid = __popcll(m << (63 - t)) - 1;
        runid_lds[t] = rid;
        if (flag) { rdst_lds[rid] = dsv; rbound_lds[rid] = 0; }
        int nd = __popcll(m);
        if (t == 0) {
            ndist_lds = nd;
            if (m_off > 0 && (int)(spak2[m_off - 1].x >> 16) == dsv)
                rbound_lds[0] = 1;
        }
        if (t == MT - 1) {
            if (m_off + MT < E_TOTAL &&
                (int)(spak2[m_off + MT].x >> 16) == dsv)
                rbound_lds[nd - 1] = 1;
        }
    }
    __syncthreads();

    const int c = 16 * w2 + l15;

    float4 va[2];
    #pragma unroll
    for (int it = 0; it < 2; ++it) {
        int idx = it * 512 + t;
        int e = idx >> 4;
        va[it] = ((const float4*)(ea + (size_t)eid_lds[e] * DE))[idx & 15];
    }
    unsigned int ps[16], pd[16];
    #pragma unroll
    for (int i = 0; i < 4; ++i)
        #pragma unroll
        for (int j = 0; j < 4; ++j) {
            int e = i * 16 + quad * 4 + j;
            ps[i * 4 + j] = nodeP32[(size_t)src_lds[e] * 256 + 128 + c];
            pd[i * 4 + j] = nodeP32[(size_t)dst_lds[e] * 256 + c];
        }
    {
        int nd = ndist_lds;
        int col = t & 127, rb = t >> 7;
        for (int r = rb; r < nd; r += 4) sumb[r][col] = 0.f;
    }
    #pragma unroll
    for (int it = 0; it < 2; ++it) {
        int idx = it * 512 + t;
        int e = idx >> 4, kq = idx & 15;
        int g = kq >> 1;
        int col = ((g & 7) ^ (e & 7)) * 8 + (kq & 1) * 4;
        *((uint2*)&A_lds[e * DE + col]) = pkbf4(va[it]);
    }

    f32x4 acc[4][2] = {};
    const unsigned short* Bp[2];
    #pragma unroll
    for (int u = 0; u < 2; ++u) {
        int nt = w2 + u * 8;
        Bp[u] = WtE + (size_t)(nt * 16 + l15) * DE + quad * 8;
    }
    __syncthreads();

    #pragma unroll
    for (int ks = 0; ks < 2; ++ks) {
        bf16x8 af[4], bfr[2];
        #pragma unroll
        for (int i = 0; i < 4; ++i) {
            int m = i * 16 + l15;
            int g = 4 * ks + quad;
            int col = ((g & 7) ^ (l15 & 7)) * 8;
            af[i] = *((const bf16x8*)&A_lds[m * DE + col]);
        }
        #pragma unroll
        for (int u = 0; u < 2; ++u)
            bfr[u] = *((const bf16x8*)(Bp[u] + ks * 32));
        #pragma unroll
        for (int i = 0; i < 4; ++i)
            #pragma unroll
            for (int u = 0; u < 2; ++u)
                acc[i][u] = __builtin_amdgcn_mfma_f32_16x16x32_bf16(
                    af[i], bfr[u], acc[i][u], 0, 0, 0);
    }

    int rprev = -1;
    float s0 = 0.f, nf = 0.f, ns = 0.f;
    #pragma unroll
    for (int i = 0; i < 4; ++i)
        #pragma unroll
        for (int j = 0; j < 4; ++j) {
            int e = i * 16 + quad * 4 + j;
            int rid = runid_lds[e];
            if (rid != rprev) {
                if (rprev >= 0) atomicAdd(&sumb[rprev][c], s0);
                rprev = rid; s0 = 0.f;
                unsigned int pk = pd[i * 4 + j];
                nf = bf2f((unsigned short)(pk & 0xffffu));
                ns = bf2f((unsigned short)(pk >> 16));
            }
            unsigned int pp = ps[i * 4 + j];
            float f  = acc[i][0][j] + nf + bf2f((unsigned short)(pp & 0xffffu));
            float sg = acc[i][1][j] + ns + bf2f((unsigned short)(pp >> 16));
            s0 += fast_rcp(1.f + __expf(-f)) *
                  (fmaxf(sg, 0.f) + __logf(1.f + __expf(-fabsf(sg))));
        }
    atomicAdd(&sumb[rprev][c], s0);
    __syncthreads();

    {
        int nd = ndist_lds;
        int col = t & 127, rb = t >> 7;
        for (int r = rb; r < nd; r += 4) {
            float v = sumb[r][col];
            float* op = out + (size_t)rdst_lds[r] * DD + col;
            if (rbound_lds[r]) atomicAdd(op, v);
            else *op += v;
        }
    }
}

__global__ void relu_kernel(float* __restrict__ out) {
    int id = blockIdx.x * 256 + threadIdx.x;
    if (id < NN * DD / 4) {
        float4 v = ((float4*)out)[id];
        v.x = fmaxf(v.x, 0.0f); v.y = fmaxf(v.y, 0.0f);
        v.z = fmaxf(v.z, 0.0f); v.w = fmaxf(v.w, 0.0f);
        ((float4*)out)[id] = v;
    }
}

// ===================== last-resort fallback (unsorted, K=320) ==============

__global__ void prep_fb(const float* __restrict__ x,
                        const float* __restrict__ W_f,
                        const float* __restrict__ W_s,
                        unsigned short* __restrict__ Wt,
                        float* __restrict__ out) {
    int id = blockIdx.x * 256 + threadIdx.x;
    if (id < NN * DD / 4)
        ((float4*)out)[id] = ((const float4*)x)[id];
    if (id < 2 * DD * ZDIM) {
        int n = id / ZDIM, k = id - n * ZDIM;
        float wv = (n < DD) ? W_f[k * DD + n] : W_s[k * DD + (n - DD)];
        Wt[n * ZDIM + k] = f2bf(wv);
    }
}

__global__ __launch_bounds__(256, 3)
void edge_fb(const float* __restrict__ x,
             const int* __restrict__ ei,
             const float* __restrict__ ea,
             const unsigned short* __restrict__ Wt,
             const float* __restrict__ bf_,
             const float* __restrict__ bs_,
             float* __restrict__ out) {
    __shared__ unsigned short A_lds[MT * ZDIM];
    __shared__ int dst_lds[MT];
    __shared__ int src_lds[MT];

    const int t = threadIdx.x;
    const int m_off = blockIdx.x * MT;
    const int lane = t & 63, w = t >> 6, l15 = lane & 15, quad = lane >> 4;

    if (t < MT) dst_lds[t] = ei[E_TOTAL + m_off + t];
    else if (t < 2 * MT) src_lds[t - MT] = ei[m_off + (t - MT)];
    __syncthreads();

    #pragma unroll
    for (int it = 0; it < 4; ++it) {
        int idx = it * 256 + t;
        int e = idx >> 4, kq = idx & 15;
        float4 v = ((const float4*)(ea + (size_t)(m_off + e) * DE))[kq];
        int g = 32 + (kq >> 1);
        int col = ((g & ~7) | ((g & 7) ^ (e & 7))) * 8 + (kq & 1) * 4;
        *((uint2*)&A_lds[e * ZDIM + col]) = pkbf4(v);
    }
    #pragma unroll
    for (int it = 0; it < 8; ++it) {
        int idx = it * 256 + t;
        int e = idx >> 5, kq = idx & 31;
        float4 v = ((const float4*)(x + (size_t)dst_lds[e] * DD))[kq];
        int g = kq >> 1;
        int col = ((g & ~7) | ((g & 7) ^ (e & 7))) * 8 + (kq & 1) * 4;
        *((uint2*)&A_lds[e * ZDIM + col]) = pkbf4(v);
    }
    #pragma unroll
    for (int it = 0; it < 8; ++it) {
        int idx = it * 256 + t;
        int e = idx >> 5, kq = idx & 31;
        float4 v = ((const float4*)(x + (size_t)src_lds[e] * DD))[kq];
        int g = 16 + (kq >> 1);
        int col = ((g & ~7) | ((g & 7) ^ (e & 7))) * 8 + (kq & 1) * 4;
        *((uint2*)&A_lds[e * ZDIM + col]) = pkbf4(v);
    }

    f32x4 acc[4][4] = {};
    const int nt0 = 2 * w;
    const unsigned short* Bp[4];
    #pragma unroll
    for (int u = 0; u < 4; ++u) {
        int nt = nt0 + ((u < 2) ? u : (6 + u));
        Bp[u] = Wt + (size_t)(nt * 16 + l15) * ZDIM + quad * 8;
    }
    __syncthreads();

    #pragma unroll
    for (int ks = 0; ks < 10; ++ks) {
        bf16x8 af[4], bfr[4];
        #pragma unroll
        for (int i = 0; i < 4; ++i) {
            int m = i * 16 + l15;
            int g = 4 * ks + quad;
            int col = ((g & ~7) | ((g & 7) ^ (l15 & 7))) * 8;
            af[i] = *((const bf16x8*)&A_lds[m * ZDIM + col]);
        }
        #pragma unroll
        for (int u = 0; u < 4; ++u)
            bfr[u] = *((const bf16x8*)(Bp[u] + ks * 32));
        #pragma unroll
        for (int i = 0; i < 4; ++i)
            #pragma unroll
            for (int u = 0; u < 4; ++u)
                acc[i][u] = __builtin_amdgcn_mfma_f32_16x16x32_bf16(
                    af[i], bfr[u], acc[i][u], 0, 0, 0);
    }

    const int c0 = 32 * w + l15, c1 = c0 + 16;
    const float bf0 = bf_[c0], bs0 = bs_[c0], bf1 = bf_[c1], bs1 = bs_[c1];
    #pragma unroll
    for (int i = 0; i < 4; ++i)
        #pragma unroll
        for (int j = 0; j < 4; ++j) {
            int e = i * 16 + quad * 4 + j;
            float* op = out + (size_t)dst_lds[e] * DD;
            float f0 = acc[i][0][j] + bf0;
            float sg0 = acc[i][2][j] + bs0;
            atomicAdd(op + c0, fast_rcp(1.f + __expf(-f0)) *
                (fmaxf(sg0, 0.f) + __logf(1.f + __expf(-fabsf(sg0)))));
            float f1 = acc[i][1][j] + bf1;
            float sg1 = acc[i][3][j] + bs1;
            atomicAdd(op + c1, fast_rcp(1.f + __expf(-f1)) *
                (fmaxf(sg1, 0.f) + __logf(1.f + __expf(-fabsf(sg1)))));
        }
}

// ===================== launch =====================

extern "C" void kernel_launch(void* const* d_in, const int* in_sizes, int n_in,
                              void* d_out, int out_size, void* d_ws, size_t ws_size,
                              hipStream_t stream) {
    (void)in_sizes; (void)n_in; (void)out_size;
    const float* x   = (const float*)d_in[0];
    const int*   ei  = (const int*)d_in[1];
    const float* ea  = (const float*)d_in[2];
    const float* W_f = (const float*)d_in[3];
    const float* b_f = (const float*)d_in[4];
    const float* W_s = (const float*)d_in[5];
    const float* b_s = (const float*)d_in[6];
    float* out = (float*)d_out;

    char* ws = (char*)d_ws;
    const size_t WS_NEED4 = 83764864;   // main: + aggr (25.6 MB)
    const size_t WS_NEED2 = 58164864;   // path2 fallback

    if (ws_size >= WS_NEED4) {
        unsigned short* WtE2   = (unsigned short*)ws;              //  32768
        unsigned short* WtN2   = (unsigned short*)(ws + 32768);    // 131072
        int*            counts = (int*)(ws + 163840);              // 200000
        int*            cursor = (int*)(ws + 363840);              // 200000
        int*            partial= (int*)(ws + 563840);              //   1024
        uint2*          spak2  = (uint2*)(ws + 564864);            // 6.4e6
        unsigned int*   nodeP32= (unsigned int*)(ws + 6964864);    // 51.2e6
        float*          aggr   = (float*)(ws + 58164864);          // 25.6e6

        hipMemsetAsync(counts, 0, NN * sizeof(int), stream);
        prep_kernel4<<<NN * DD / 4 / 256, 256, 0, stream>>>(
            ei, W_f, W_s, WtE2, WtN2, counts, aggr);
        scan_part<<<NBS, 256, 0, stream>>>(counts, partial);
        scan_final2<<<NBS, 256, 0, stream>>>(counts, partial, cursor);
        scatter_kernel<<<(E_TOTAL + 255) / 256, 256, 0, stream>>>(ei, cursor, spak2);
        node_kernel3<<<(NN + MT - 1) / MT, 512, 0, stream>>>(
            x, WtN2, b_f, b_s, nodeP32);
        edge_kernel6<<<E_TOTAL / MT, 512, 0, stream>>>(
            ea, WtE2, nodeP32, aggr, spak2);
        relu_kernel4<<<6250, 256, 0, stream>>>(x, aggr, out);
    } else if (ws_size >= WS_NEED2) {
        unsigned short* WtE2   = (unsigned short*)ws;              //  32768
        unsigned short* WtN2   = (unsigned short*)(ws + 32768);    // 131072
        int*            counts = (int*)(ws + 163840);              // 200000
        int*            cursor = (int*)(ws + 363840);              // 200000
        int*            partial= (int*)(ws + 563840);              //   1024
        uint2*          spak2  = (uint2*)(ws + 564864);            // 6.4e6
        unsigned int*   nodeP32= (unsigned int*)(ws + 6964864);    // 51.2e6

        hipMemsetAsync(counts, 0, NN * sizeof(int), stream);
        prep_kernel2<<<NN * DD / 4 / 256, 256, 0, stream>>>(
            x, ei, W_f, W_s, WtE2, WtN2, counts, out);
        scan_part<<<NBS, 256, 0, stream>>>(counts, partial);
        scan_top<<<1, 256, 0, stream>>>(partial);
        scan_final<<<NBS, 256, 0, stream>>>(counts, partial, cursor);
        scatter_kernel<<<(E_TOTAL + 255) / 256, 256, 0, stream>>>(ei, cursor, spak2);
        dim3 ng((NN + MT - 1) / MT, 2);
        node_kernel2<<<ng, 256, 0, stream>>>(x, WtN2, b_f, b_s, nodeP32);
        edge_kernel2<<<E_TOTAL / MT, 512, 0, stream>>>(
            ea, WtE2, nodeP32, out, spak2);
        relu_kernel<<<6250, 256, 0, stream>>>(out);
    } else {
        unsigned short* Wt = (unsigned short*)ws;   // 163840 B
        prep_fb<<<6250, 256, 0, stream>>>(x, W_f, W_s, Wt, out);
        edge_fb<<<E_TOTAL / MT, 256, 0, stream>>>(x, ei, ea, Wt, b_f, b_s, out);
        relu_kernel<<<6250, 256, 0, stream>>>(out);
    }
}

// Round 9
// 662.659 us; speedup vs baseline: 1.2035x; 1.2035x over previous
//
#include <hip/hip_runtime.h>
#include <hip/hip_bf16.h>

#define E_TOTAL   800000
#define NN        50000
#define DD        128
#define DE        64
#define ZDIM      320
#define MT        64
#define SB        16       // sumb rows kept in LDS (overflow -> global atomics)
#define NBS       196      // scan blocks: 196*256 = 50176 >= NN

typedef short bf16x8 __attribute__((ext_vector_type(8)));
typedef float f32x4  __attribute__((ext_vector_type(4)));

__device__ __forceinline__ unsigned short f2bf(float f) {
    union { float f; unsigned int u; } v; v.f = f;
    unsigned int u = v.u;
    return (unsigned short)((u + 0x7fffu + ((u >> 16) & 1u)) >> 16);
}

__device__ __forceinline__ float bf2f(unsigned short h) {
    union { unsigned u; float f; } v; v.u = ((unsigned)h) << 16; return v.f;
}

__device__ __forceinline__ unsigned pkbf2(float a, float b) {
    __hip_bfloat162 h = __float22bfloat162_rn(make_float2(a, b));
    unsigned u; __builtin_memcpy(&u, &h, 4); return u;
}

__device__ __forceinline__ uint2 pkbf4(float4 v) {
    uint2 r; r.x = pkbf2(v.x, v.y); r.y = pkbf2(v.z, v.w); return r;
}

__device__ __forceinline__ float fast_rcp(float x) {
#if __has_builtin(__builtin_amdgcn_rcpf)
    return __builtin_amdgcn_rcpf(x);
#else
    return 1.0f / x;
#endif
}

// ===================== sorting helpers =====================

__global__ void scan_part(const int* __restrict__ counts, int* __restrict__ partial) {
    __shared__ int red[256];
    int t = threadIdx.x, k = blockIdx.x * 256 + t;
    red[t] = (k < NN) ? counts[k] : 0;
    __syncthreads();
    for (int d = 128; d > 0; d >>= 1) {
        if (t < d) red[t] += red[t + d];
        __syncthreads();
    }
    if (t == 0) partial[blockIdx.x] = red[0];
}

__global__ void scan_top(int* __restrict__ partial) {
    __shared__ int s[256];
    int t = threadIdx.x;
    int v = (t < NBS) ? partial[t] : 0;
    s[t] = v; __syncthreads();
    for (int d = 1; d < 256; d <<= 1) {
        int a = (t >= d) ? s[t - d] : 0;
        __syncthreads();
        s[t] += a;
        __syncthreads();
    }
    if (t < NBS) partial[t] = s[t] - v;
}

__global__ void scan_final(const int* __restrict__ counts,
                           const int* __restrict__ partial,
                           int* __restrict__ cursor) {
    __shared__ int s[256];
    int t = threadIdx.x, k = blockIdx.x * 256 + t;
    int v = (k < NN) ? counts[k] : 0;
    s[t] = v; __syncthreads();
    for (int d = 1; d < 256; d <<= 1) {
        int a = (t >= d) ? s[t - d] : 0;
        __syncthreads();
        s[t] += a;
        __syncthreads();
    }
    if (k < NN) cursor[k] = partial[blockIdx.x] + s[t] - v;
}

// scan_top folded in — each block prefix-sums the 196 partials itself.
__global__ void scan_final2(const int* __restrict__ counts,
                            const int* __restrict__ partial,
                            int* __restrict__ cursor) {
    __shared__ int s[256], p2[256], orig[256];
    int t = threadIdx.x, k = blockIdx.x * 256 + t;
    int pv = (t < NBS) ? partial[t] : 0;
    p2[t] = pv; orig[t] = pv; __syncthreads();
    for (int d = 1; d < 256; d <<= 1) {
        int a = (t >= d) ? p2[t - d] : 0;
        __syncthreads();
        p2[t] += a;
        __syncthreads();
    }
    int blkoff = p2[blockIdx.x] - orig[blockIdx.x];
    int v = (k < NN) ? counts[k] : 0;
    s[t] = v; __syncthreads();
    for (int d = 1; d < 256; d <<= 1) {
        int a = (t >= d) ? s[t - d] : 0;
        __syncthreads();
        s[t] += a;
        __syncthreads();
    }
    if (k < NN) cursor[k] = blkoff + s[t] - v;
}

// spak2[pos] = { (dst<<16)|src , eid }
__global__ void scatter_kernel(const int* __restrict__ ei, int* __restrict__ cursor,
                               uint2* __restrict__ spak2) {
    int e = blockIdx.x * 256 + threadIdx.x;
    if (e < E_TOTAL) {
        int d = ei[E_TOTAL + e];
        int pos = atomicAdd(&cursor[d], 1);
        uint2 p; p.x = ((unsigned)d << 16) | (unsigned)ei[e]; p.y = (unsigned)e;
        spak2[pos] = p;
    }
}

// ===================== main-path prep =====================

// aggr <- 0 ; hist(dst) ; WtE[n][k]=W[256+k][n'] ; WtN[part][n][k]=W[part*128+k][n']
__global__ void prep_kernel4(const int* __restrict__ ei,
                             const float* __restrict__ W_f,
                             const float* __restrict__ W_s,
                             unsigned short* __restrict__ WtE,
                             unsigned short* __restrict__ WtN,
                             int* __restrict__ counts,
                             float* __restrict__ aggr) {
    int id = blockIdx.x * 256 + threadIdx.x;          // grid = NN*DD/4 exactly
    float4 z; z.x = 0.f; z.y = 0.f; z.z = 0.f; z.w = 0.f;
    ((float4*)aggr)[id] = z;
    if (id < E_TOTAL) atomicAdd(&counts[ei[E_TOTAL + id]], 1);
    if (id < 256 * DE) {
        int n = id >> 6, k = id & 63;
        int ok = 2 * DD + k;
        float wv = (n < DD) ? W_f[ok * DD + n] : W_s[ok * DD + (n - DD)];
        WtE[id] = f2bf(wv);
    } else if (id < 256 * DE + 2 * 256 * DD) {
        int id2 = id - 256 * DE;
        int part = id2 >> 15;
        int r = id2 & 32767;
        int n = r >> 7, k = r & 127;
        int ok = part * DD + k;
        float wv = (n < DD) ? W_f[ok * DD + n] : W_s[ok * DD + (n - DD)];
        WtN[id2] = f2bf(wv);
    }
}

// nodeP32[node*256 + part*128 + c] = pkbf2(f_c, s_c); part0=dst(+bias), part1=src.
// Both projections in ONE 512-thread block sharing a single x-tile staging.
__global__ __launch_bounds__(512, 4)
void node_kernel3(const float* __restrict__ x,
                  const unsigned short* __restrict__ WtN,
                  const float* __restrict__ bf_, const float* __restrict__ bs_,
                  unsigned int* __restrict__ nodeP32) {
    __shared__ unsigned short A_lds[MT * DD];  // 16 KB
    const int t = threadIdx.x;
    const int m_off = blockIdx.x * MT;
    const int lane = t & 63, w8 = t >> 6;
    const int part = w8 >> 2, w = w8 & 3;
    const int l15 = lane & 15, quad = lane >> 4;

    #pragma unroll
    for (int it = 0; it < 4; ++it) {
        int idx = it * 512 + t;
        int e = idx >> 5, kq = idx & 31;
        int row = m_off + e; if (row >= NN) row = NN - 1;
        float4 v = ((const float4*)(x + (size_t)row * DD))[kq];
        int g = kq >> 1;
        int col = ((g & ~7) | ((g & 7) ^ (e & 7))) * 8 + (kq & 1) * 4;
        *((uint2*)&A_lds[e * DD + col]) = pkbf4(v);
    }

    f32x4 acc[4][4] = {};
    const int nt0 = 2 * w;
    const unsigned short* Bp[4];
    #pragma unroll
    for (int u = 0; u < 4; ++u) {
        int nt = nt0 + ((u < 2) ? u : (6 + u));
        Bp[u] = WtN + (size_t)part * (256 * DD) +
                (size_t)(nt * 16 + l15) * DD + quad * 8;
    }
    __syncthreads();

    #pragma unroll
    for (int ks = 0; ks < 4; ++ks) {
        bf16x8 af[4], bfr[4];
        #pragma unroll
        for (int i = 0; i < 4; ++i) {
            int m = i * 16 + l15;
            int g = 4 * ks + quad;
            int col = ((g & ~7) | ((g & 7) ^ (l15 & 7))) * 8;
            af[i] = *((const bf16x8*)&A_lds[m * DD + col]);
        }
        #pragma unroll
        for (int u = 0; u < 4; ++u)
            bfr[u] = *((const bf16x8*)(Bp[u] + ks * 32));
        #pragma unroll
        for (int i = 0; i < 4; ++i)
            #pragma unroll
            for (int u = 0; u < 4; ++u)
                acc[i][u] = __builtin_amdgcn_mfma_f32_16x16x32_bf16(
                    af[i], bfr[u], acc[i][u], 0, 0, 0);
    }

    const int c0 = 32 * w + l15, c1 = c0 + 16;
    const float bf0 = part ? 0.f : bf_[c0], bs0 = part ? 0.f : bs_[c0];
    const float bf1 = part ? 0.f : bf_[c1], bs1 = part ? 0.f : bs_[c1];
    #pragma unroll
    for (int i = 0; i < 4; ++i)
        #pragma unroll
        for (int j = 0; j < 4; ++j) {
            int e = i * 16 + quad * 4 + j;
            int row = m_off + e;
            if (row < NN) {
                unsigned int* np = nodeP32 + (size_t)row * 256 + part * 128;
                np[c0] = pkbf2(acc[i][0][j] + bf0, acc[i][2][j] + bs0);
                np[c1] = pkbf2(acc[i][1][j] + bf1, acc[i][3][j] + bs1);
            }
        }
}

// ===================== main edge kernel (R9: 75% occupancy, reg-fit) =====
// R8 proved 90% occupancy reachable with small sumb, but (512,8)'s 64-reg
// cap spilled ps/pd to scratch (2 GB HBM traffic). R9 targets the 3-block
// step (75%): __launch_bounds__(512,6) = 85-reg budget, and trims ~12 regs
// by prefetching only the 4 GROUP-LEADER dst projections (pd[4], R1-proven)
// with inline loads at rare intra-group run boundaries. ps[16] stays.
// MUST NOT spill — check WRITE_SIZE ~31 MB (spill shows as +100s of MB).
__global__ __launch_bounds__(512, 6)
void edge_kernel7(const float* __restrict__ ea,
                  const unsigned short* __restrict__ WtE,
                  const unsigned int* __restrict__ nodeP32,
                  float* __restrict__ aggr,
                  const uint2* __restrict__ spak2) {
    __shared__ float sumb[SB][DD];              // 8 KB run-sum buffer
    __shared__ unsigned short A_lds[MT * DE];   // 8192 B
    __shared__ int dst_lds[MT];
    __shared__ int src_lds[MT];
    __shared__ int eid_lds[MT];
    __shared__ int runid_lds[MT];
    __shared__ int rdst_lds[MT];
    __shared__ int rbound_lds[MT];
    __shared__ int ndist_lds;

    const int t = threadIdx.x;
    const int m_off = blockIdx.x * MT;
    const int lane = t & 63, w2 = t >> 6, l15 = lane & 15, quad = lane >> 4;

    if (t < MT) {                               // wave 0 exactly
        uint2 p = spak2[m_off + t];
        int dsv = (int)(p.x >> 16);
        dst_lds[t] = dsv;
        src_lds[t] = (int)(p.x & 0xffffu);
        eid_lds[t] = (int)p.y;
        int updsv = __shfl_up(dsv, 1);
        int flag = (t == 0 || dsv != updsv) ? 1 : 0;
        unsigned long long m = __ballot(flag != 0);
        int rid = __popcll(m << (63 - t)) - 1;  // inclusive-scan(flag) - 1
        runid_lds[t] = rid;
        if (flag) { rdst_lds[rid] = dsv; rbound_lds[rid] = 0; }
        int nd = __popcll(m);
        if (t == 0) {
            ndist_lds = nd;
            if (m_off > 0 && (int)(spak2[m_off - 1].x >> 16) == dsv)
                rbound_lds[0] = 1;              // run 0 continues prev block
        }
        if (t == MT - 1) {
            if (m_off + MT < E_TOTAL &&
                (int)(spak2[m_off + MT].x >> 16) == dsv)
                rbound_lds[nd - 1] = 1;         // last run continues next block
        }
    }
    __syncthreads();

    const int c = 16 * w2 + l15;                 // this thread's output col

    // 1) ea loads first (oldest in vm queue -> staging wait is cheap)
    float4 va[2];
    #pragma unroll
    for (int it = 0; it < 2; ++it) {
        int idx = it * 512 + t;
        int e = idx >> 4;
        va[it] = ((const float4*)(ea + (size_t)eid_lds[e] * DE))[idx & 15];
    }
    // 2) prefetch epilogue gathers: all 16 src-proj + 4 group-leader dst-proj
    unsigned int ps[16], pd[4];
    #pragma unroll
    for (int i = 0; i < 4; ++i) {
        #pragma unroll
        for (int j = 0; j < 4; ++j)
            ps[i * 4 + j] = nodeP32[(size_t)src_lds[i * 16 + quad * 4 + j] * 256
                                    + 128 + c];
        pd[i] = nodeP32[(size_t)dst_lds[i * 16 + quad * 4] * 256 + c];
    }
    // 2b) zero sumb (SB*DD = 2048 = 4 per thread)
    {
        int col = t & 127;
        #pragma unroll
        for (int r = t >> 7; r < SB; r += 4) sumb[r][col] = 0.f;
    }
    // 3) cvt + LDS store of ea -> cols [0,64)
    #pragma unroll
    for (int it = 0; it < 2; ++it) {
        int idx = it * 512 + t;
        int e = idx >> 4, kq = idx & 15;
        int g = kq >> 1;                              // 0..7
        int col = ((g & 7) ^ (e & 7)) * 8 + (kq & 1) * 4;
        *((uint2*)&A_lds[e * DE + col]) = pkbf4(va[it]);
    }

    f32x4 acc[4][2] = {};
    const unsigned short* Bp[2];
    #pragma unroll
    for (int u = 0; u < 2; ++u) {
        int nt = w2 + u * 8;                      // u0: f-cols, u1: s-cols
        Bp[u] = WtE + (size_t)(nt * 16 + l15) * DE + quad * 8;
    }
    __syncthreads();

    #pragma unroll
    for (int ks = 0; ks < 2; ++ks) {
        bf16x8 af[4], bfr[2];
        #pragma unroll
        for (int i = 0; i < 4; ++i) {
            int m = i * 16 + l15;
            int g = 4 * ks + quad;                    // 0..7
            int col = ((g & 7) ^ (l15 & 7)) * 8;
            af[i] = *((const bf16x8*)&A_lds[m * DE + col]);
        }
        #pragma unroll
        for (int u = 0; u < 2; ++u)
            bfr[u] = *((const bf16x8*)(Bp[u] + ks * 32));
        #pragma unroll
        for (int i = 0; i < 4; ++i)
            #pragma unroll
            for (int u = 0; u < 2; ++u)
                acc[i][u] = __builtin_amdgcn_mfma_f32_16x16x32_bf16(
                    af[i], bfr[u], acc[i][u], 0, 0, 0);
    }

    int rprev = -1, dprev = -1;
    float s0 = 0.f, nf = 0.f, ns = 0.f;
    #pragma unroll
    for (int i = 0; i < 4; ++i)
        #pragma unroll
        for (int j = 0; j < 4; ++j) {
            int e = i * 16 + quad * 4 + j;
            int rid = runid_lds[e];
            if (rid != rprev) {
                if (rprev >= 0) {
                    if (rprev < SB) atomicAdd(&sumb[rprev][c], s0);
                    else atomicAdd(aggr + (size_t)dprev * DD + c, s0);
                }
                rprev = rid; s0 = 0.f;
                dprev = dst_lds[e];
                unsigned int pk;
                if (j == 0) pk = pd[i];               // prefetched group leader
                else pk = nodeP32[(size_t)dprev * 256 + c];
                nf = bf2f((unsigned short)(pk & 0xffffu));
                ns = bf2f((unsigned short)(pk >> 16));
            }
            unsigned int pp = ps[i * 4 + j];
            float f  = acc[i][0][j] + nf + bf2f((unsigned short)(pp & 0xffffu));
            float sg = acc[i][1][j] + ns + bf2f((unsigned short)(pp >> 16));
            s0 += fast_rcp(1.f + __expf(-f)) *
                  (fmaxf(sg, 0.f) + __logf(1.f + __expf(-fabsf(sg))));
        }
    if (rprev < SB) atomicAdd(&sumb[rprev][c], s0);
    else atomicAdd(aggr + (size_t)dprev * DD + c, s0);
    __syncthreads();

    // write-out: one op per (run, col). Interior run => single-writer STORE.
    {
        int nd = ndist_lds; if (nd > SB) nd = SB;
        int col = t & 127, rb = t >> 7;
        for (int r = rb; r < nd; r += 4) {
            float v = sumb[r][col];
            float* op = aggr + (size_t)rdst_lds[r] * DD + col;
            if (rbound_lds[r]) atomicAdd(op, v);
            else *op = v;
        }
    }
}

// out = relu(x + aggr)
__global__ void relu_kernel4(const float* __restrict__ x,
                             const float* __restrict__ aggr,
                             float* __restrict__ out) {
    int id = blockIdx.x * 256 + threadIdx.x;
    if (id < NN * DD / 4) {
        float4 xv = ((const float4*)x)[id];
        float4 av = ((const float4*)aggr)[id];
        float4 v;
        v.x = fmaxf(xv.x + av.x, 0.0f); v.y = fmaxf(xv.y + av.y, 0.0f);
        v.z = fmaxf(xv.z + av.z, 0.0f); v.w = fmaxf(xv.w + av.w, 0.0f);
        ((float4*)out)[id] = v;
    }
}

// ===================== path2 fallback (R4 exact) =====================

__global__ void prep_kernel2(const float* __restrict__ x,
                             const int* __restrict__ ei,
                             const float* __restrict__ W_f,
                             const float* __restrict__ W_s,
                             unsigned short* __restrict__ WtE,
                             unsigned short* __restrict__ WtN,
                             int* __restrict__ counts,
                             float* __restrict__ out) {
    int id = blockIdx.x * 256 + threadIdx.x;
    ((float4*)out)[id] = ((const float4*)x)[id];
    if (id < E_TOTAL) atomicAdd(&counts[ei[E_TOTAL + id]], 1);
    if (id < 256 * DE) {
        int n = id >> 6, k = id & 63;
        int ok = 2 * DD + k;
        float wv = (n < DD) ? W_f[ok * DD + n] : W_s[ok * DD + (n - DD)];
        WtE[id] = f2bf(wv);
    } else if (id < 256 * DE + 2 * 256 * DD) {
        int id2 = id - 256 * DE;
        int part = id2 >> 15;
        int r = id2 & 32767;
        int n = r >> 7, k = r & 127;
        int ok = part * DD + k;
        float wv = (n < DD) ? W_f[ok * DD + n] : W_s[ok * DD + (n - DD)];
        WtN[id2] = f2bf(wv);
    }
}

__global__ __launch_bounds__(256, 4)
void node_kernel2(const float* __restrict__ x,
                  const unsigned short* __restrict__ WtN,
                  const float* __restrict__ bf_, const float* __restrict__ bs_,
                  unsigned int* __restrict__ nodeP32) {
    __shared__ unsigned short A_lds[MT * DD];
    const int t = threadIdx.x;
    const int m_off = blockIdx.x * MT;
    const int part = blockIdx.y;
    const int lane = t & 63, w = t >> 6, l15 = lane & 15, quad = lane >> 4;

    #pragma unroll
    for (int it = 0; it < 8; ++it) {
        int idx = it * 256 + t;
        int e = idx >> 5, kq = idx & 31;
        int row = m_off + e; if (row >= NN) row = NN - 1;
        float4 v = ((const float4*)(x + (size_t)row * DD))[kq];
        int g = kq >> 1;
        int col = ((g & ~7) | ((g & 7) ^ (e & 7))) * 8 + (kq & 1) * 4;
        *((uint2*)&A_lds[e * DD + col]) = pkbf4(v);
    }

    f32x4 acc[4][4] = {};
    const int nt0 = 2 * w;
    const unsigned short* Bp[4];
    #pragma unroll
    for (int u = 0; u < 4; ++u) {
        int nt = nt0 + ((u < 2) ? u : (6 + u));
        Bp[u] = WtN + (size_t)part * (256 * DD) +
                (size_t)(nt * 16 + l15) * DD + quad * 8;
    }
    __syncthreads();

    #pragma unroll
    for (int ks = 0; ks < 4; ++ks) {
        bf16x8 af[4], bfr[4];
        #pragma unroll
        for (int i = 0; i < 4; ++i) {
            int m = i * 16 + l15;
            int g = 4 * ks + quad;
            int col = ((g & ~7) | ((g & 7) ^ (l15 & 7))) * 8;
            af[i] = *((const bf16x8*)&A_lds[m * DD + col]);
        }
        #pragma unroll
        for (int u = 0; u < 4; ++u)
            bfr[u] = *((const bf16x8*)(Bp[u] + ks * 32));
        #pragma unroll
        for (int i = 0; i < 4; ++i)
            #pragma unroll
            for (int u = 0; u < 4; ++u)
                acc[i][u] = __builtin_amdgcn_mfma_f32_16x16x32_bf16(
                    af[i], bfr[u], acc[i][u], 0, 0, 0);
    }

    const int c0 = 32 * w + l15, c1 = c0 + 16;
    const float bf0 = part ? 0.f : bf_[c0], bs0 = part ? 0.f : bs_[c0];
    const float bf1 = part ? 0.f : bf_[c1], bs1 = part ? 0.f : bs_[c1];
    #pragma unroll
    for (int i = 0; i < 4; ++i)
        #pragma unroll
        for (int j = 0; j < 4; ++j) {
            int e = i * 16 + quad * 4 + j;
            int row = m_off + e;
            if (row < NN) {
                unsigned int* np = nodeP32 + (size_t)row * 256 + part * 128;
                np[c0] = pkbf2(acc[i][0][j] + bf0, acc[i][2][j] + bs0);
                np[c1] = pkbf2(acc[i][1][j] + bf1, acc[i][3][j] + bs1);
            }
        }
}

__global__ __launch_bounds__(512, 4)
void edge_kernel2(const float* __restrict__ ea,
                  const unsigned short* __restrict__ WtE,
                  const unsigned int* __restrict__ nodeP32,
                  float* __restrict__ out,
                  const uint2* __restrict__ spak2) {
    __shared__ float sumb[MT][DD];
    __shared__ unsigned short A_lds[MT * DE];
    __shared__ int dst_lds[MT];
    __shared__ int src_lds[MT];
    __shared__ int eid_lds[MT];
    __shared__ int runid_lds[MT];
    __shared__ int rdst_lds[MT];
    __shared__ int rbound_lds[MT];
    __shared__ int ndist_lds;

    const int t = threadIdx.x;
    const int m_off = blockIdx.x * MT;
    const int lane = t & 63, w2 = t >> 6, l15 = lane & 15, quad = lane >> 4;

    if (t < MT) {
        uint2 p = spak2[m_off + t];
        int dsv = (int)(p.x >> 16);
        dst_lds[t] = dsv;
        src_lds[t] = (int)(p.x & 0xffffu);
        eid_lds[t] = (int)p.y;
        int updsv = __shfl_up(dsv, 1);
        int flag = (t == 0 || dsv != updsv) ? 1 : 0;
        unsigned long long m = __ballot(flag != 0);
        int rid = __popcll(m << (63 - t)) - 1;
        runid_lds[t] = rid;
        if (flag) { rdst_lds[rid] = dsv; rbound_lds[rid] = 0; }
        int nd = __popcll(m);
        if (t == 0) {
            ndist_lds = nd;
            if (m_off > 0 && (int)(spak2[m_off - 1].x >> 16) == dsv)
                rbound_lds[0] = 1;
        }
        if (t == MT - 1) {
            if (m_off + MT < E_TOTAL &&
                (int)(spak2[m_off + MT].x >> 16) == dsv)
                rbound_lds[nd - 1] = 1;
        }
    }
    __syncthreads();

    const int c = 16 * w2 + l15;

    float4 va[2];
    #pragma unroll
    for (int it = 0; it < 2; ++it) {
        int idx = it * 512 + t;
        int e = idx >> 4;
        va[it] = ((const float4*)(ea + (size_t)eid_lds[e] * DE))[idx & 15];
    }
    unsigned int ps[16], pd[16];
    #pragma unroll
    for (int i = 0; i < 4; ++i)
        #pragma unroll
        for (int j = 0; j < 4; ++j) {
            int e = i * 16 + quad * 4 + j;
            ps[i * 4 + j] = nodeP32[(size_t)src_lds[e] * 256 + 128 + c];
            pd[i * 4 + j] = nodeP32[(size_t)dst_lds[e] * 256 + c];
        }
    {
        int nd = ndist_lds;
        int col = t & 127, rb = t >> 7;
        for (int r = rb; r < nd; r += 4) sumb[r][col] = 0.f;
    }
    #pragma unroll
    for (int it = 0; it < 2; ++it) {
        int idx = it * 512 + t;
        int e = idx >> 4, kq = idx & 15;
        int g = kq >> 1;
        int col = ((g & 7) ^ (e & 7)) * 8 + (kq & 1) * 4;
        *((uint2*)&A_lds[e * DE + col]) = pkbf4(va[it]);
    }

    f32x4 acc[4][2] = {};
    const unsigned short* Bp[2];
    #pragma unroll
    for (int u = 0; u < 2; ++u) {
        int nt = w2 + u * 8;
        Bp[u] = WtE + (size_t)(nt * 16 + l15) * DE + quad * 8;
    }
    __syncthreads();

    #pragma unroll
    for (int ks = 0; ks < 2; ++ks) {
        bf16x8 af[4], bfr[2];
        #pragma unroll
        for (int i = 0; i < 4; ++i) {
            int m = i * 16 + l15;
            int g = 4 * ks + quad;
            int col = ((g & 7) ^ (l15 & 7)) * 8;
            af[i] = *((const bf16x8*)&A_lds[m * DE + col]);
        }
        #pragma unroll
        for (int u = 0; u < 2; ++u)
            bfr[u] = *((const bf16x8*)(Bp[u] + ks * 32));
        #pragma unroll
        for (int i = 0; i < 4; ++i)
            #pragma unroll
            for (int u = 0; u < 2; ++u)
                acc[i][u] = __builtin_amdgcn_mfma_f32_16x16x32_bf16(
                    af[i], bfr[u], acc[i][u], 0, 0, 0);
    }

    int rprev = -1;
    float s0 = 0.f, nf = 0.f, ns = 0.f;
    #pragma unroll
    for (int i = 0; i < 4; ++i)
        #pragma unroll
        for (int j = 0; j < 4; ++j) {
            int e = i * 16 + quad * 4 + j;
            int rid = runid_lds[e];
            if (rid != rprev) {
                if (rprev >= 0) atomicAdd(&sumb[rprev][c], s0);
                rprev = rid; s0 = 0.f;
                unsigned int pk = pd[i * 4 + j];
                nf = bf2f((unsigned short)(pk & 0xffffu));
                ns = bf2f((unsigned short)(pk >> 16));
            }
            unsigned int pp = ps[i * 4 + j];
            float f  = acc[i][0][j] + nf + bf2f((unsigned short)(pp & 0xffffu));
            float sg = acc[i][1][j] + ns + bf2f((unsigned short)(pp >> 16));
            s0 += fast_rcp(1.f + __expf(-f)) *
                  (fmaxf(sg, 0.f) + __logf(1.f + __expf(-fabsf(sg))));
        }
    atomicAdd(&sumb[rprev][c], s0);
    __syncthreads();

    {
        int nd = ndist_lds;
        int col = t & 127, rb = t >> 7;
        for (int r = rb; r < nd; r += 4) {
            float v = sumb[r][col];
            float* op = out + (size_t)rdst_lds[r] * DD + col;
            if (rbound_lds[r]) atomicAdd(op, v);
            else *op += v;
        }
    }
}

__global__ void relu_kernel(float* __restrict__ out) {
    int id = blockIdx.x * 256 + threadIdx.x;
    if (id < NN * DD / 4) {
        float4 v = ((float4*)out)[id];
        v.x = fmaxf(v.x, 0.0f); v.y = fmaxf(v.y, 0.0f);
        v.z = fmaxf(v.z, 0.0f); v.w = fmaxf(v.w, 0.0f);
        ((float4*)out)[id] = v;
    }
}

// ===================== last-resort fallback (unsorted, K=320) ==============

__global__ void prep_fb(const float* __restrict__ x,
                        const float* __restrict__ W_f,
                        const float* __restrict__ W_s,
                        unsigned short* __restrict__ Wt,
                        float* __restrict__ out) {
    int id = blockIdx.x * 256 + threadIdx.x;
    if (id < NN * DD / 4)
        ((float4*)out)[id] = ((const float4*)x)[id];
    if (id < 2 * DD * ZDIM) {
        int n = id / ZDIM, k = id - n * ZDIM;
        float wv = (n < DD) ? W_f[k * DD + n] : W_s[k * DD + (n - DD)];
        Wt[n * ZDIM + k] = f2bf(wv);
    }
}

__global__ __launch_bounds__(256, 3)
void edge_fb(const float* __restrict__ x,
             const int* __restrict__ ei,
             const float* __restrict__ ea,
             const unsigned short* __restrict__ Wt,
             const float* __restrict__ bf_,
             const float* __restrict__ bs_,
             float* __restrict__ out) {
    __shared__ unsigned short A_lds[MT * ZDIM];
    __shared__ int dst_lds[MT];
    __shared__ int src_lds[MT];

    const int t = threadIdx.x;
    const int m_off = blockIdx.x * MT;
    const int lane = t & 63, w = t >> 6, l15 = lane & 15, quad = lane >> 4;

    if (t < MT) dst_lds[t] = ei[E_TOTAL + m_off + t];
    else if (t < 2 * MT) src_lds[t - MT] = ei[m_off + (t - MT)];
    __syncthreads();

    #pragma unroll
    for (int it = 0; it < 4; ++it) {
        int idx = it * 256 + t;
        int e = idx >> 4, kq = idx & 15;
        float4 v = ((const float4*)(ea + (size_t)(m_off + e) * DE))[kq];
        int g = 32 + (kq >> 1);
        int col = ((g & ~7) | ((g & 7) ^ (e & 7))) * 8 + (kq & 1) * 4;
        *((uint2*)&A_lds[e * ZDIM + col]) = pkbf4(v);
    }
    #pragma unroll
    for (int it = 0; it < 8; ++it) {
        int idx = it * 256 + t;
        int e = idx >> 5, kq = idx & 31;
        float4 v = ((const float4*)(x + (size_t)dst_lds[e] * DD))[kq];
        int g = kq >> 1;
        int col = ((g & ~7) | ((g & 7) ^ (e & 7))) * 8 + (kq & 1) * 4;
        *((uint2*)&A_lds[e * ZDIM + col]) = pkbf4(v);
    }
    #pragma unroll
    for (int it = 0; it < 8; ++it) {
        int idx = it * 256 + t;
        int e = idx >> 5, kq = idx & 31;
        float4 v = ((const float4*)(x + (size_t)src_lds[e] * DD))[kq];
        int g = 16 + (kq >> 1);
        int col = ((g & ~7) | ((g & 7) ^ (e & 7))) * 8 + (kq & 1) * 4;
        *((uint2*)&A_lds[e * ZDIM + col]) = pkbf4(v);
    }

    f32x4 acc[4][4] = {};
    const int nt0 = 2 * w;
    const unsigned short* Bp[4];
    #pragma unroll
    for (int u = 0; u < 4; ++u) {
        int nt = nt0 + ((u < 2) ? u : (6 + u));
        Bp[u] = Wt + (size_t)(nt * 16 + l15) * ZDIM + quad * 8;
    }
    __syncthreads();

    #pragma unroll
    for (int ks = 0; ks < 10; ++ks) {
        bf16x8 af[4], bfr[4];
        #pragma unroll
        for (int i = 0; i < 4; ++i) {
            int m = i * 16 + l15;
            int g = 4 * ks + quad;
            int col = ((g & ~7) | ((g & 7) ^ (l15 & 7))) * 8;
            af[i] = *((const bf16x8*)&A_lds[m * ZDIM + col]);
        }
        #pragma unroll
        for (int u = 0; u < 4; ++u)
            bfr[u] = *((const bf16x8*)(Bp[u] + ks * 32));
        #pragma unroll
        for (int i = 0; i < 4; ++i)
            #pragma unroll
            for (int u = 0; u < 4; ++u)
                acc[i][u] = __builtin_amdgcn_mfma_f32_16x16x32_bf16(
                    af[i], bfr[u], acc[i][u], 0, 0, 0);
    }

    const int c0 = 32 * w + l15, c1 = c0 + 16;
    const float bf0 = bf_[c0], bs0 = bs_[c0], bf1 = bf_[c1], bs1 = bs_[c1];
    #pragma unroll
    for (int i = 0; i < 4; ++i)
        #pragma unroll
        for (int j = 0; j < 4; ++j) {
            int e = i * 16 + quad * 4 + j;
            float* op = out + (size_t)dst_lds[e] * DD;
            float f0 = acc[i][0][j] + bf0;
            float sg0 = acc[i][2][j] + bs0;
            atomicAdd(op + c0, fast_rcp(1.f + __expf(-f0)) *
                (fmaxf(sg0, 0.f) + __logf(1.f + __expf(-fabsf(sg0)))));
            float f1 = acc[i][1][j] + bf1;
            float sg1 = acc[i][3][j] + bs1;
            atomicAdd(op + c1, fast_rcp(1.f + __expf(-f1)) *
                (fmaxf(sg1, 0.f) + __logf(1.f + __expf(-fabsf(sg1)))));
        }
}

// ===================== launch =====================

extern "C" void kernel_launch(void* const* d_in, const int* in_sizes, int n_in,
                              void* d_out, int out_size, void* d_ws, size_t ws_size,
                              hipStream_t stream) {
    (void)in_sizes; (void)n_in; (void)out_size;
    const float* x   = (const float*)d_in[0];
    const int*   ei  = (const int*)d_in[1];
    const float* ea  = (const float*)d_in[2];
    const float* W_f = (const float*)d_in[3];
    const float* b_f = (const float*)d_in[4];
    const float* W_s = (const float*)d_in[5];
    const float* b_s = (const float*)d_in[6];
    float* out = (float*)d_out;

    char* ws = (char*)d_ws;
    const size_t WS_NEED4 = 83764864;   // main: + aggr (25.6 MB)
    const size_t WS_NEED2 = 58164864;   // path2 fallback

    if (ws_size >= WS_NEED4) {
        unsigned short* WtE2   = (unsigned short*)ws;              //  32768
        unsigned short* WtN2   = (unsigned short*)(ws + 32768);    // 131072
        int*            counts = (int*)(ws + 163840);              // 200000
        int*            cursor = (int*)(ws + 363840);              // 200000
        int*            partial= (int*)(ws + 563840);              //   1024
        uint2*          spak2  = (uint2*)(ws + 564864);            // 6.4e6
        unsigned int*   nodeP32= (unsigned int*)(ws + 6964864);    // 51.2e6
        float*          aggr   = (float*)(ws + 58164864);          // 25.6e6

        hipMemsetAsync(counts, 0, NN * sizeof(int), stream);
        prep_kernel4<<<NN * DD / 4 / 256, 256, 0, stream>>>(
            ei, W_f, W_s, WtE2, WtN2, counts, aggr);
        scan_part<<<NBS, 256, 0, stream>>>(counts, partial);
        scan_final2<<<NBS, 256, 0, stream>>>(counts, partial, cursor);
        scatter_kernel<<<(E_TOTAL + 255) / 256, 256, 0, stream>>>(ei, cursor, spak2);
        node_kernel3<<<(NN + MT - 1) / MT, 512, 0, stream>>>(
            x, WtN2, b_f, b_s, nodeP32);
        edge_kernel7<<<E_TOTAL / MT, 512, 0, stream>>>(
            ea, WtE2, nodeP32, aggr, spak2);
        relu_kernel4<<<6250, 256, 0, stream>>>(x, aggr, out);
    } else if (ws_size >= WS_NEED2) {
        unsigned short* WtE2   = (unsigned short*)ws;              //  32768
        unsigned short* WtN2   = (unsigned short*)(ws + 32768);    // 131072
        int*            counts = (int*)(ws + 163840);              // 200000
        int*            cursor = (int*)(ws + 363840);              // 200000
        int*            partial= (int*)(ws + 563840);              //   1024
        uint2*          spak2  = (uint2*)(ws + 564864);            // 6.4e6
        unsigned int*   nodeP32= (unsigned int*)(ws + 6964864);    // 51.2e6

        hipMemsetAsync(counts, 0, NN * sizeof(int), stream);
        prep_kernel2<<<NN * DD / 4 / 256, 256, 0, stream>>>(
            x, ei, W_f, W_s, WtE2, WtN2, counts, out);
        scan_part<<<NBS, 256, 0, stream>>>(counts, partial);
        scan_top<<<1, 256, 0, stream>>>(partial);
        scan_final<<<NBS, 256, 0, stream>>>(counts, partial, cursor);
        scatter_kernel<<<(E_TOTAL + 255) / 256, 256, 0, stream>>>(ei, cursor, spak2);
        dim3 ng((NN + MT - 1) / MT, 2);
        node_kernel2<<<ng, 256, 0, stream>>>(x, WtN2, b_f, b_s, nodeP32);
        edge_kernel2<<<E_TOTAL / MT, 512, 0, stream>>>(
            ea, WtE2, nodeP32, out, spak2);
        relu_kernel<<<6250, 256, 0, stream>>>(out);
    } else {
        unsigned short* Wt = (unsigned short*)ws;   // 163840 B
        prep_fb<<<6250, 256, 0, stream>>>(x, W_f, W_s, Wt, out);
        edge_fb<<<E_TOTAL / MT, 256, 0, stream>>>(x, ei, ea, Wt, b_f, b_s, out);
        relu_kernel<<<6250, 256, 0, stream>>>(out);
    }
}

// Round 10
// 589.717 us; speedup vs baseline: 1.3524x; 1.1237x over previous
//
#include <hip/hip_runtime.h>
#include <hip/hip_bf16.h>

#define E_TOTAL   800000
#define NN        50000
#define DD        128
#define DE        64
#define ZDIM      320
#define MT        64
#define SB        16       // sumb rows kept in LDS (overflow -> global atomics)
#define NBS       196      // scan blocks: 196*256 = 50176 >= NN

typedef short bf16x8 __attribute__((ext_vector_type(8)));
typedef float f32x4  __attribute__((ext_vector_type(4)));

__device__ __forceinline__ unsigned short f2bf(float f) {
    union { float f; unsigned int u; } v; v.f = f;
    unsigned int u = v.u;
    return (unsigned short)((u + 0x7fffu + ((u >> 16) & 1u)) >> 16);
}

__device__ __forceinline__ float bf2f(unsigned short h) {
    union { unsigned u; float f; } v; v.u = ((unsigned)h) << 16; return v.f;
}

__device__ __forceinline__ unsigned pkbf2(float a, float b) {
    __hip_bfloat162 h = __float22bfloat162_rn(make_float2(a, b));
    unsigned u; __builtin_memcpy(&u, &h, 4); return u;
}

__device__ __forceinline__ uint2 pkbf4(float4 v) {
    uint2 r; r.x = pkbf2(v.x, v.y); r.y = pkbf2(v.z, v.w); return r;
}

__device__ __forceinline__ float fast_rcp(float x) {
#if __has_builtin(__builtin_amdgcn_rcpf)
    return __builtin_amdgcn_rcpf(x);
#else
    return 1.0f / x;
#endif
}

// ===================== sorting helpers =====================

__global__ void scan_part(const int* __restrict__ counts, int* __restrict__ partial) {
    __shared__ int red[256];
    int t = threadIdx.x, k = blockIdx.x * 256 + t;
    red[t] = (k < NN) ? counts[k] : 0;
    __syncthreads();
    for (int d = 128; d > 0; d >>= 1) {
        if (t < d) red[t] += red[t + d];
        __syncthreads();
    }
    if (t == 0) partial[blockIdx.x] = red[0];
}

__global__ void scan_top(int* __restrict__ partial) {
    __shared__ int s[256];
    int t = threadIdx.x;
    int v = (t < NBS) ? partial[t] : 0;
    s[t] = v; __syncthreads();
    for (int d = 1; d < 256; d <<= 1) {
        int a = (t >= d) ? s[t - d] : 0;
        __syncthreads();
        s[t] += a;
        __syncthreads();
    }
    if (t < NBS) partial[t] = s[t] - v;
}

__global__ void scan_final(const int* __restrict__ counts,
                           const int* __restrict__ partial,
                           int* __restrict__ cursor) {
    __shared__ int s[256];
    int t = threadIdx.x, k = blockIdx.x * 256 + t;
    int v = (k < NN) ? counts[k] : 0;
    s[t] = v; __syncthreads();
    for (int d = 1; d < 256; d <<= 1) {
        int a = (t >= d) ? s[t - d] : 0;
        __syncthreads();
        s[t] += a;
        __syncthreads();
    }
    if (k < NN) cursor[k] = partial[blockIdx.x] + s[t] - v;
}

// scan_top folded in — each block prefix-sums the 196 partials itself.
__global__ void scan_final2(const int* __restrict__ counts,
                            const int* __restrict__ partial,
                            int* __restrict__ cursor) {
    __shared__ int s[256], p2[256], orig[256];
    int t = threadIdx.x, k = blockIdx.x * 256 + t;
    int pv = (t < NBS) ? partial[t] : 0;
    p2[t] = pv; orig[t] = pv; __syncthreads();
    for (int d = 1; d < 256; d <<= 1) {
        int a = (t >= d) ? p2[t - d] : 0;
        __syncthreads();
        p2[t] += a;
        __syncthreads();
    }
    int blkoff = p2[blockIdx.x] - orig[blockIdx.x];
    int v = (k < NN) ? counts[k] : 0;
    s[t] = v; __syncthreads();
    for (int d = 1; d < 256; d <<= 1) {
        int a = (t >= d) ? s[t - d] : 0;
        __syncthreads();
        s[t] += a;
        __syncthreads();
    }
    if (k < NN) cursor[k] = blkoff + s[t] - v;
}

// spak2[pos] = { (dst<<16)|src , eid }
__global__ void scatter_kernel(const int* __restrict__ ei, int* __restrict__ cursor,
                               uint2* __restrict__ spak2) {
    int e = blockIdx.x * 256 + threadIdx.x;
    if (e < E_TOTAL) {
        int d = ei[E_TOTAL + e];
        int pos = atomicAdd(&cursor[d], 1);
        uint2 p; p.x = ((unsigned)d << 16) | (unsigned)ei[e]; p.y = (unsigned)e;
        spak2[pos] = p;
    }
}

// ===================== main-path prep =====================

// aggr <- 0 ; hist(dst) ; WtE[n][k]=W[256+k][n'] ; WtN[part][n][k]=W[part*128+k][n']
__global__ void prep_kernel4(const int* __restrict__ ei,
                             const float* __restrict__ W_f,
                             const float* __restrict__ W_s,
                             unsigned short* __restrict__ WtE,
                             unsigned short* __restrict__ WtN,
                             int* __restrict__ counts,
                             float* __restrict__ aggr) {
    int id = blockIdx.x * 256 + threadIdx.x;          // grid = NN*DD/4 exactly
    float4 z; z.x = 0.f; z.y = 0.f; z.z = 0.f; z.w = 0.f;
    ((float4*)aggr)[id] = z;
    if (id < E_TOTAL) atomicAdd(&counts[ei[E_TOTAL + id]], 1);
    if (id < 256 * DE) {
        int n = id >> 6, k = id & 63;
        int ok = 2 * DD + k;
        float wv = (n < DD) ? W_f[ok * DD + n] : W_s[ok * DD + (n - DD)];
        WtE[id] = f2bf(wv);
    } else if (id < 256 * DE + 2 * 256 * DD) {
        int id2 = id - 256 * DE;
        int part = id2 >> 15;
        int r = id2 & 32767;
        int n = r >> 7, k = r & 127;
        int ok = part * DD + k;
        float wv = (n < DD) ? W_f[ok * DD + n] : W_s[ok * DD + (n - DD)];
        WtN[id2] = f2bf(wv);
    }
}

// nodeP32[node*256 + part*128 + c] = pkbf2(f_c, s_c); part0=dst(+bias), part1=src.
// Both projections in ONE 512-thread block sharing a single x-tile staging.
__global__ __launch_bounds__(512, 4)
void node_kernel3(const float* __restrict__ x,
                  const unsigned short* __restrict__ WtN,
                  const float* __restrict__ bf_, const float* __restrict__ bs_,
                  unsigned int* __restrict__ nodeP32) {
    __shared__ unsigned short A_lds[MT * DD];  // 16 KB
    const int t = threadIdx.x;
    const int m_off = blockIdx.x * MT;
    const int lane = t & 63, w8 = t >> 6;
    const int part = w8 >> 2, w = w8 & 3;
    const int l15 = lane & 15, quad = lane >> 4;

    #pragma unroll
    for (int it = 0; it < 4; ++it) {
        int idx = it * 512 + t;
        int e = idx >> 5, kq = idx & 31;
        int row = m_off + e; if (row >= NN) row = NN - 1;
        float4 v = ((const float4*)(x + (size_t)row * DD))[kq];
        int g = kq >> 1;
        int col = ((g & ~7) | ((g & 7) ^ (e & 7))) * 8 + (kq & 1) * 4;
        *((uint2*)&A_lds[e * DD + col]) = pkbf4(v);
    }

    f32x4 acc[4][4] = {};
    const int nt0 = 2 * w;
    const unsigned short* Bp[4];
    #pragma unroll
    for (int u = 0; u < 4; ++u) {
        int nt = nt0 + ((u < 2) ? u : (6 + u));
        Bp[u] = WtN + (size_t)part * (256 * DD) +
                (size_t)(nt * 16 + l15) * DD + quad * 8;
    }
    __syncthreads();

    #pragma unroll
    for (int ks = 0; ks < 4; ++ks) {
        bf16x8 af[4], bfr[4];
        #pragma unroll
        for (int i = 0; i < 4; ++i) {
            int m = i * 16 + l15;
            int g = 4 * ks + quad;
            int col = ((g & ~7) | ((g & 7) ^ (l15 & 7))) * 8;
            af[i] = *((const bf16x8*)&A_lds[m * DD + col]);
        }
        #pragma unroll
        for (int u = 0; u < 4; ++u)
            bfr[u] = *((const bf16x8*)(Bp[u] + ks * 32));
        #pragma unroll
        for (int i = 0; i < 4; ++i)
            #pragma unroll
            for (int u = 0; u < 4; ++u)
                acc[i][u] = __builtin_amdgcn_mfma_f32_16x16x32_bf16(
                    af[i], bfr[u], acc[i][u], 0, 0, 0);
    }

    const int c0 = 32 * w + l15, c1 = c0 + 16;
    const float bf0 = part ? 0.f : bf_[c0], bs0 = part ? 0.f : bs_[c0];
    const float bf1 = part ? 0.f : bf_[c1], bs1 = part ? 0.f : bs_[c1];
    #pragma unroll
    for (int i = 0; i < 4; ++i)
        #pragma unroll
        for (int j = 0; j < 4; ++j) {
            int e = i * 16 + quad * 4 + j;
            int row = m_off + e;
            if (row < NN) {
                unsigned int* np = nodeP32 + (size_t)row * 256 + part * 128;
                np[c0] = pkbf2(acc[i][0][j] + bf0, acc[i][2][j] + bs0);
                np[c1] = pkbf2(acc[i][1][j] + bf1, acc[i][3][j] + bs1);
            }
        }
}

// ===================== main edge kernel (R10: 3 blocks/CU, reg margin) =====
// R9's (512,6) spilled because ps[16]+pd[4] put the total at exactly the
// 84-reg budget. R10 shrinks the epilogue prefetch to the R1-proven 2-deep
// ps pipeline (psA[4]/psB[4]) + pd[4] group leaders = 12 regs (was 20):
// total ~76, margin ~8 under the cliff. Group i's transcendentals cover
// group i+2's gather latency. MUST be clean: WRITE_SIZE ~31 MB.
#define PS_LOAD(PS, I)                                                         \
    _Pragma("unroll")                                                          \
    for (int j = 0; j < 4; ++j)                                                \
        PS[j] = nodeP32[(size_t)src_lds[(I) * 16 + quad * 4 + j] * 256         \
                        + 128 + c];

#define PS_PROC(PS, I)                                                         \
    _Pragma("unroll")                                                          \
    for (int j = 0; j < 4; ++j) {                                              \
        int e = (I) * 16 + quad * 4 + j;                                       \
        int rid = runid_lds[e];                                                \
        if (rid != rprev) {                                                    \
            if (rprev >= 0) {                                                  \
                if (rprev < SB) atomicAdd(&sumb[rprev][c], s0);                \
                else atomicAdd(aggr + (size_t)dprev * DD + c, s0);             \
            }                                                                  \
            rprev = rid; s0 = 0.f;                                             \
            dprev = dst_lds[e];                                                \
            unsigned pk;                                                       \
            if (j == 0) pk = pd[I];            /* prefetched group leader */   \
            else pk = nodeP32[(size_t)dprev * 256 + c];                        \
            nf = bf2f((unsigned short)(pk & 0xffffu));                         \
            ns = bf2f((unsigned short)(pk >> 16));                             \
        }                                                                      \
        unsigned pp = PS[j];                                                   \
        float f  = acc[(I)][0][j] + nf + bf2f((unsigned short)(pp & 0xffffu)); \
        float sg = acc[(I)][1][j] + ns + bf2f((unsigned short)(pp >> 16));     \
        s0 += fast_rcp(1.f + __expf(-f)) *                                     \
              (fmaxf(sg, 0.f) + __logf(1.f + __expf(-fabsf(sg))));             \
    }

__global__ __launch_bounds__(512, 6)
void edge_kernel8(const float* __restrict__ ea,
                  const unsigned short* __restrict__ WtE,
                  const unsigned int* __restrict__ nodeP32,
                  float* __restrict__ aggr,
                  const uint2* __restrict__ spak2) {
    __shared__ float sumb[SB][DD];              // 8 KB run-sum buffer
    __shared__ unsigned short A_lds[MT * DE];   // 8192 B
    __shared__ int dst_lds[MT];
    __shared__ int src_lds[MT];
    __shared__ int eid_lds[MT];
    __shared__ int runid_lds[MT];
    __shared__ int rdst_lds[MT];
    __shared__ int rbound_lds[MT];
    __shared__ int ndist_lds;

    const int t = threadIdx.x;
    const int m_off = blockIdx.x * MT;
    const int lane = t & 63, w2 = t >> 6, l15 = lane & 15, quad = lane >> 4;

    if (t < MT) {                               // wave 0 exactly
        uint2 p = spak2[m_off + t];
        int dsv = (int)(p.x >> 16);
        dst_lds[t] = dsv;
        src_lds[t] = (int)(p.x & 0xffffu);
        eid_lds[t] = (int)p.y;
        int updsv = __shfl_up(dsv, 1);
        int flag = (t == 0 || dsv != updsv) ? 1 : 0;
        unsigned long long m = __ballot(flag != 0);
        int rid = __popcll(m << (63 - t)) - 1;  // inclusive-scan(flag) - 1
        runid_lds[t] = rid;
        if (flag) { rdst_lds[rid] = dsv; rbound_lds[rid] = 0; }
        int nd = __popcll(m);
        if (t == 0) {
            ndist_lds = nd;
            if (m_off > 0 && (int)(spak2[m_off - 1].x >> 16) == dsv)
                rbound_lds[0] = 1;              // run 0 continues prev block
        }
        if (t == MT - 1) {
            if (m_off + MT < E_TOTAL &&
                (int)(spak2[m_off + MT].x >> 16) == dsv)
                rbound_lds[nd - 1] = 1;         // last run continues next block
        }
    }
    __syncthreads();

    const int c = 16 * w2 + l15;                 // this thread's output col

    // 1) ea loads first (oldest in vm queue -> staging wait is cheap)
    float4 va[2];
    #pragma unroll
    for (int it = 0; it < 2; ++it) {
        int idx = it * 512 + t;
        int e = idx >> 4;
        va[it] = ((const float4*)(ea + (size_t)eid_lds[e] * DE))[idx & 15];
    }
    // 2) prefetch group-leader dst projections (4 regs)
    unsigned int pd[4];
    #pragma unroll
    for (int i = 0; i < 4; ++i)
        pd[i] = nodeP32[(size_t)dst_lds[i * 16 + quad * 4] * 256 + c];
    // 2b) zero sumb (SB*DD = 2048 = 4 per thread)
    {
        int col = t & 127;
        #pragma unroll
        for (int r = t >> 7; r < SB; r += 4) sumb[r][col] = 0.f;
    }
    // 3) cvt + LDS store of ea -> cols [0,64)
    #pragma unroll
    for (int it = 0; it < 2; ++it) {
        int idx = it * 512 + t;
        int e = idx >> 4, kq = idx & 15;
        int g = kq >> 1;                              // 0..7
        int col = ((g & 7) ^ (e & 7)) * 8 + (kq & 1) * 4;
        *((uint2*)&A_lds[e * DE + col]) = pkbf4(va[it]);
    }

    f32x4 acc[4][2] = {};
    const unsigned short* Bp[2];
    #pragma unroll
    for (int u = 0; u < 2; ++u) {
        int nt = w2 + u * 8;                      // u0: f-cols, u1: s-cols
        Bp[u] = WtE + (size_t)(nt * 16 + l15) * DE + quad * 8;
    }
    __syncthreads();

    #pragma unroll
    for (int ks = 0; ks < 2; ++ks) {
        bf16x8 af[4], bfr[2];
        #pragma unroll
        for (int i = 0; i < 4; ++i) {
            int m = i * 16 + l15;
            int g = 4 * ks + quad;                    // 0..7
            int col = ((g & 7) ^ (l15 & 7)) * 8;
            af[i] = *((const bf16x8*)&A_lds[m * DE + col]);
        }
        #pragma unroll
        for (int u = 0; u < 2; ++u)
            bfr[u] = *((const bf16x8*)(Bp[u] + ks * 32));
        #pragma unroll
        for (int i = 0; i < 4; ++i)
            #pragma unroll
            for (int u = 0; u < 2; ++u)
                acc[i][u] = __builtin_amdgcn_mfma_f32_16x16x32_bf16(
                    af[i], bfr[u], acc[i][u], 0, 0, 0);
    }

    // epilogue: 2-deep ps pipeline (R1 pattern) — group i's transcendentals
    // hide group i+2's src-projection gather latency.
    int rprev = -1, dprev = -1;
    float s0 = 0.f, nf = 0.f, ns = 0.f;
    unsigned int psA[4], psB[4];
    PS_LOAD(psA, 0)
    PS_LOAD(psB, 1)
    PS_PROC(psA, 0)
    PS_LOAD(psA, 2)
    PS_PROC(psB, 1)
    PS_LOAD(psB, 3)
    PS_PROC(psA, 2)
    PS_PROC(psB, 3)
    if (rprev < SB) atomicAdd(&sumb[rprev][c], s0);
    else atomicAdd(aggr + (size_t)dprev * DD + c, s0);
    __syncthreads();

    // write-out: one op per (run, col). Interior run => single-writer STORE.
    {
        int nd = ndist_lds; if (nd > SB) nd = SB;
        int col = t & 127, rb = t >> 7;
        for (int r = rb; r < nd; r += 4) {
            float v = sumb[r][col];
            float* op = aggr + (size_t)rdst_lds[r] * DD + col;
            if (rbound_lds[r]) atomicAdd(op, v);
            else *op = v;
        }
    }
}

// out = relu(x + aggr)
__global__ void relu_kernel4(const float* __restrict__ x,
                             const float* __restrict__ aggr,
                             float* __restrict__ out) {
    int id = blockIdx.x * 256 + threadIdx.x;
    if (id < NN * DD / 4) {
        float4 xv = ((const float4*)x)[id];
        float4 av = ((const float4*)aggr)[id];
        float4 v;
        v.x = fmaxf(xv.x + av.x, 0.0f); v.y = fmaxf(xv.y + av.y, 0.0f);
        v.z = fmaxf(xv.z + av.z, 0.0f); v.w = fmaxf(xv.w + av.w, 0.0f);
        ((float4*)out)[id] = v;
    }
}

// ===================== path2 fallback (R4 exact) =====================

__global__ void prep_kernel2(const float* __restrict__ x,
                             const int* __restrict__ ei,
                             const float* __restrict__ W_f,
                             const float* __restrict__ W_s,
                             unsigned short* __restrict__ WtE,
                             unsigned short* __restrict__ WtN,
                             int* __restrict__ counts,
                             float* __restrict__ out) {
    int id = blockIdx.x * 256 + threadIdx.x;
    ((float4*)out)[id] = ((const float4*)x)[id];
    if (id < E_TOTAL) atomicAdd(&counts[ei[E_TOTAL + id]], 1);
    if (id < 256 * DE) {
        int n = id >> 6, k = id & 63;
        int ok = 2 * DD + k;
        float wv = (n < DD) ? W_f[ok * DD + n] : W_s[ok * DD + (n - DD)];
        WtE[id] = f2bf(wv);
    } else if (id < 256 * DE + 2 * 256 * DD) {
        int id2 = id - 256 * DE;
        int part = id2 >> 15;
        int r = id2 & 32767;
        int n = r >> 7, k = r & 127;
        int ok = part * DD + k;
        float wv = (n < DD) ? W_f[ok * DD + n] : W_s[ok * DD + (n - DD)];
        WtN[id2] = f2bf(wv);
    }
}

__global__ __launch_bounds__(256, 4)
void node_kernel2(const float* __restrict__ x,
                  const unsigned short* __restrict__ WtN,
                  const float* __restrict__ bf_, const float* __restrict__ bs_,
                  unsigned int* __restrict__ nodeP32) {
    __shared__ unsigned short A_lds[MT * DD];
    const int t = threadIdx.x;
    const int m_off = blockIdx.x * MT;
    const int part = blockIdx.y;
    const int lane = t & 63, w = t >> 6, l15 = lane & 15, quad = lane >> 4;

    #pragma unroll
    for (int it = 0; it < 8; ++it) {
        int idx = it * 256 + t;
        int e = idx >> 5, kq = idx & 31;
        int row = m_off + e; if (row >= NN) row = NN - 1;
        float4 v = ((const float4*)(x + (size_t)row * DD))[kq];
        int g = kq >> 1;
        int col = ((g & ~7) | ((g & 7) ^ (e & 7))) * 8 + (kq & 1) * 4;
        *((uint2*)&A_lds[e * DD + col]) = pkbf4(v);
    }

    f32x4 acc[4][4] = {};
    const int nt0 = 2 * w;
    const unsigned short* Bp[4];
    #pragma unroll
    for (int u = 0; u < 4; ++u) {
        int nt = nt0 + ((u < 2) ? u : (6 + u));
        Bp[u] = WtN + (size_t)part * (256 * DD) +
                (size_t)(nt * 16 + l15) * DD + quad * 8;
    }
    __syncthreads();

    #pragma unroll
    for (int ks = 0; ks < 4; ++ks) {
        bf16x8 af[4], bfr[4];
        #pragma unroll
        for (int i = 0; i < 4; ++i) {
            int m = i * 16 + l15;
            int g = 4 * ks + quad;
            int col = ((g & ~7) | ((g & 7) ^ (l15 & 7))) * 8;
            af[i] = *((const bf16x8*)&A_lds[m * DD + col]);
        }
        #pragma unroll
        for (int u = 0; u < 4; ++u)
            bfr[u] = *((const bf16x8*)(Bp[u] + ks * 32));
        #pragma unroll
        for (int i = 0; i < 4; ++i)
            #pragma unroll
            for (int u = 0; u < 4; ++u)
                acc[i][u] = __builtin_amdgcn_mfma_f32_16x16x32_bf16(
                    af[i], bfr[u], acc[i][u], 0, 0, 0);
    }

    const int c0 = 32 * w + l15, c1 = c0 + 16;
    const float bf0 = part ? 0.f : bf_[c0], bs0 = part ? 0.f : bs_[c0];
    const float bf1 = part ? 0.f : bf_[c1], bs1 = part ? 0.f : bs_[c1];
    #pragma unroll
    for (int i = 0; i < 4; ++i)
        #pragma unroll
        for (int j = 0; j < 4; ++j) {
            int e = i * 16 + quad * 4 + j;
            int row = m_off + e;
            if (row < NN) {
                unsigned int* np = nodeP32 + (size_t)row * 256 + part * 128;
                np[c0] = pkbf2(acc[i][0][j] + bf0, acc[i][2][j] + bs0);
                np[c1] = pkbf2(acc[i][1][j] + bf1, acc[i][3][j] + bs1);
            }
        }
}

__global__ __launch_bounds__(512, 4)
void edge_kernel2(const float* __restrict__ ea,
                  const unsigned short* __restrict__ WtE,
                  const unsigned int* __restrict__ nodeP32,
                  float* __restrict__ out,
                  const uint2* __restrict__ spak2) {
    __shared__ float sumb[MT][DD];
    __shared__ unsigned short A_lds[MT * DE];
    __shared__ int dst_lds[MT];
    __shared__ int src_lds[MT];
    __shared__ int eid_lds[MT];
    __shared__ int runid_lds[MT];
    __shared__ int rdst_lds[MT];
    __shared__ int rbound_lds[MT];
    __shared__ int ndist_lds;

    const int t = threadIdx.x;
    const int m_off = blockIdx.x * MT;
    const int lane = t & 63, w2 = t >> 6, l15 = lane & 15, quad = lane >> 4;

    if (t < MT) {
        uint2 p = spak2[m_off + t];
        int dsv = (int)(p.x >> 16);
        dst_lds[t] = dsv;
        src_lds[t] = (int)(p.x & 0xffffu);
        eid_lds[t] = (int)p.y;
        int updsv = __shfl_up(dsv, 1);
        int flag = (t == 0 || dsv != updsv) ? 1 : 0;
        unsigned long long m = __ballot(flag != 0);
        int rid = __popcll(m << (63 - t)) - 1;
        runid_lds[t] = rid;
        if (flag) { rdst_lds[rid] = dsv; rbound_lds[rid] = 0; }
        int nd = __popcll(m);
        if (t == 0) {
            ndist_lds = nd;
            if (m_off > 0 && (int)(spak2[m_off - 1].x >> 16) == dsv)
                rbound_lds[0] = 1;
        }
        if (t == MT - 1) {
            if (m_off + MT < E_TOTAL &&
                (int)(spak2[m_off + MT].x >> 16) == dsv)
                rbound_lds[nd - 1] = 1;
        }
    }
    __syncthreads();

    const int c = 16 * w2 + l15;

    float4 va[2];
    #pragma unroll
    for (int it = 0; it < 2; ++it) {
        int idx = it * 512 + t;
        int e = idx >> 4;
        va[it] = ((const float4*)(ea + (size_t)eid_lds[e] * DE))[idx & 15];
    }
    unsigned int ps[16], pd[16];
    #pragma unroll
    for (int i = 0; i < 4; ++i)
        #pragma unroll
        for (int j = 0; j < 4; ++j) {
            int e = i * 16 + quad * 4 + j;
            ps[i * 4 + j] = nodeP32[(size_t)src_lds[e] * 256 + 128 + c];
            pd[i * 4 + j] = nodeP32[(size_t)dst_lds[e] * 256 + c];
        }
    {
        int nd = ndist_lds;
        int col = t & 127, rb = t >> 7;
        for (int r = rb; r < nd; r += 4) sumb[r][col] = 0.f;
    }
    #pragma unroll
    for (int it = 0; it < 2; ++it) {
        int idx = it * 512 + t;
        int e = idx >> 4, kq = idx & 15;
        int g = kq >> 1;
        int col = ((g & 7) ^ (e & 7)) * 8 + (kq & 1) * 4;
        *((uint2*)&A_lds[e * DE + col]) = pkbf4(va[it]);
    }

    f32x4 acc[4][2] = {};
    const unsigned short* Bp[2];
    #pragma unroll
    for (int u = 0; u < 2; ++u) {
        int nt = w2 + u * 8;
        Bp[u] = WtE + (size_t)(nt * 16 + l15) * DE + quad * 8;
    }
    __syncthreads();

    #pragma unroll
    for (int ks = 0; ks < 2; ++ks) {
        bf16x8 af[4], bfr[2];
        #pragma unroll
        for (int i = 0; i < 4; ++i) {
            int m = i * 16 + l15;
            int g = 4 * ks + quad;
            int col = ((g & 7) ^ (l15 & 7)) * 8;
            af[i] = *((const bf16x8*)&A_lds[m * DE + col]);
        }
        #pragma unroll
        for (int u = 0; u < 2; ++u)
            bfr[u] = *((const bf16x8*)(Bp[u] + ks * 32));
        #pragma unroll
        for (int i = 0; i < 4; ++i)
            #pragma unroll
            for (int u = 0; u < 2; ++u)
                acc[i][u] = __builtin_amdgcn_mfma_f32_16x16x32_bf16(
                    af[i], bfr[u], acc[i][u], 0, 0, 0);
    }

    int rprev = -1;
    float s0 = 0.f, nf = 0.f, ns = 0.f;
    #pragma unroll
    for (int i = 0; i < 4; ++i)
        #pragma unroll
        for (int j = 0; j < 4; ++j) {
            int e = i * 16 + quad * 4 + j;
            int rid = runid_lds[e];
            if (rid != rprev) {
                if (rprev >= 0) atomicAdd(&sumb[rprev][c], s0);
                rprev = rid; s0 = 0.f;
                unsigned int pk = pd[i * 4 + j];
                nf = bf2f((unsigned short)(pk & 0xffffu));
                ns = bf2f((unsigned short)(pk >> 16));
            }
            unsigned int pp = ps[i * 4 + j];
            float f  = acc[i][0][j] + nf + bf2f((unsigned short)(pp & 0xffffu));
            float sg = acc[i][1][j] + ns + bf2f((unsigned short)(pp >> 16));
            s0 += fast_rcp(1.f + __expf(-f)) *
                  (fmaxf(sg, 0.f) + __logf(1.f + __expf(-fabsf(sg))));
        }
    atomicAdd(&sumb[rprev][c], s0);
    __syncthreads();

    {
        int nd = ndist_lds;
        int col = t & 127, rb = t >> 7;
        for (int r = rb; r < nd; r += 4) {
            float v = sumb[r][col];
            float* op = out + (size_t)rdst_lds[r] * DD + col;
            if (rbound_lds[r]) atomicAdd(op, v);
            else *op += v;
        }
    }
}

__global__ void relu_kernel(float* __restrict__ out) {
    int id = blockIdx.x * 256 + threadIdx.x;
    if (id < NN * DD / 4) {
        float4 v = ((float4*)out)[id];
        v.x = fmaxf(v.x, 0.0f); v.y = fmaxf(v.y, 0.0f);
        v.z = fmaxf(v.z, 0.0f); v.w = fmaxf(v.w, 0.0f);
        ((float4*)out)[id] = v;
    }
}

// ===================== last-resort fallback (unsorted, K=320) ==============

__global__ void prep_fb(const float* __restrict__ x,
                        const float* __restrict__ W_f,
                        const float* __restrict__ W_s,
                        unsigned short* __restrict__ Wt,
                        float* __restrict__ out) {
    int id = blockIdx.x * 256 + threadIdx.x;
    if (id < NN * DD / 4)
        ((float4*)out)[id] = ((const float4*)x)[id];
    if (id < 2 * DD * ZDIM) {
        int n = id / ZDIM, k = id - n * ZDIM;
        float wv = (n < DD) ? W_f[k * DD + n] : W_s[k * DD + (n - DD)];
        Wt[n * ZDIM + k] = f2bf(wv);
    }
}

__global__ __launch_bounds__(256, 3)
void edge_fb(const float* __restrict__ x,
             const int* __restrict__ ei,
             const float* __restrict__ ea,
             const unsigned short* __restrict__ Wt,
             const float* __restrict__ bf_,
             const float* __restrict__ bs_,
             float* __restrict__ out) {
    __shared__ unsigned short A_lds[MT * ZDIM];
    __shared__ int dst_lds[MT];
    __shared__ int src_lds[MT];

    const int t = threadIdx.x;
    const int m_off = blockIdx.x * MT;
    const int lane = t & 63, w = t >> 6, l15 = lane & 15, quad = lane >> 4;

    if (t < MT) dst_lds[t] = ei[E_TOTAL + m_off + t];
    else if (t < 2 * MT) src_lds[t - MT] = ei[m_off + (t - MT)];
    __syncthreads();

    #pragma unroll
    for (int it = 0; it < 4; ++it) {
        int idx = it * 256 + t;
        int e = idx >> 4, kq = idx & 15;
        float4 v = ((const float4*)(ea + (size_t)(m_off + e) * DE))[kq];
        int g = 32 + (kq >> 1);
        int col = ((g & ~7) | ((g & 7) ^ (e & 7))) * 8 + (kq & 1) * 4;
        *((uint2*)&A_lds[e * ZDIM + col]) = pkbf4(v);
    }
    #pragma unroll
    for (int it = 0; it < 8; ++it) {
        int idx = it * 256 + t;
        int e = idx >> 5, kq = idx & 31;
        float4 v = ((const float4*)(x + (size_t)dst_lds[e] * DD))[kq];
        int g = kq >> 1;
        int col = ((g & ~7) | ((g & 7) ^ (e & 7))) * 8 + (kq & 1) * 4;
        *((uint2*)&A_lds[e * ZDIM + col]) = pkbf4(v);
    }
    #pragma unroll
    for (int it = 0; it < 8; ++it) {
        int idx = it * 256 + t;
        int e = idx >> 5, kq = idx & 31;
        float4 v = ((const float4*)(x + (size_t)src_lds[e] * DD))[kq];
        int g = 16 + (kq >> 1);
        int col = ((g & ~7) | ((g & 7) ^ (e & 7))) * 8 + (kq & 1) * 4;
        *((uint2*)&A_lds[e * ZDIM + col]) = pkbf4(v);
    }

    f32x4 acc[4][4] = {};
    const int nt0 = 2 * w;
    const unsigned short* Bp[4];
    #pragma unroll
    for (int u = 0; u < 4; ++u) {
        int nt = nt0 + ((u < 2) ? u : (6 + u));
        Bp[u] = Wt + (size_t)(nt * 16 + l15) * ZDIM + quad * 8;
    }
    __syncthreads();

    #pragma unroll
    for (int ks = 0; ks < 10; ++ks) {
        bf16x8 af[4], bfr[4];
        #pragma unroll
        for (int i = 0; i < 4; ++i) {
            int m = i * 16 + l15;
            int g = 4 * ks + quad;
            int col = ((g & ~7) | ((g & 7) ^ (l15 & 7))) * 8;
            af[i] = *((const bf16x8*)&A_lds[m * ZDIM + col]);
        }
        #pragma unroll
        for (int u = 0; u < 4; ++u)
            bfr[u] = *((const bf16x8*)(Bp[u] + ks * 32));
        #pragma unroll
        for (int i = 0; i < 4; ++i)
            #pragma unroll
            for (int u = 0; u < 4; ++u)
                acc[i][u] = __builtin_amdgcn_mfma_f32_16x16x32_bf16(
                    af[i], bfr[u], acc[i][u], 0, 0, 0);
    }

    const int c0 = 32 * w + l15, c1 = c0 + 16;
    const float bf0 = bf_[c0], bs0 = bs_[c0], bf1 = bf_[c1], bs1 = bs_[c1];
    #pragma unroll
    for (int i = 0; i < 4; ++i)
        #pragma unroll
        for (int j = 0; j < 4; ++j) {
            int e = i * 16 + quad * 4 + j;
            float* op = out + (size_t)dst_lds[e] * DD;
            float f0 = acc[i][0][j] + bf0;
            float sg0 = acc[i][2][j] + bs0;
            atomicAdd(op + c0, fast_rcp(1.f + __expf(-f0)) *
                (fmaxf(sg0, 0.f) + __logf(1.f + __expf(-fabsf(sg0)))));
            float f1 = acc[i][1][j] + bf1;
            float sg1 = acc[i][3][j] + bs1;
            atomicAdd(op + c1, fast_rcp(1.f + __expf(-f1)) *
                (fmaxf(sg1, 0.f) + __logf(1.f + __expf(-fabsf(sg1)))));
        }
}

// ===================== launch =====================

extern "C" void kernel_launch(void* const* d_in, const int* in_sizes, int n_in,
                              void* d_out, int out_size, void* d_ws, size_t ws_size,
                              hipStream_t stream) {
    (void)in_sizes; (void)n_in; (void)out_size;
    const float* x   = (const float*)d_in[0];
    const int*   ei  = (const int*)d_in[1];
    const float* ea  = (const float*)d_in[2];
    const float* W_f = (const float*)d_in[3];
    const float* b_f = (const float*)d_in[4];
    const float* W_s = (const float*)d_in[5];
    const float* b_s = (const float*)d_in[6];
    float* out = (float*)d_out;

    char* ws = (char*)d_ws;
    const size_t WS_NEED4 = 83764864;   // main: + aggr (25.6 MB)
    const size_t WS_NEED2 = 58164864;   // path2 fallback

    if (ws_size >= WS_NEED4) {
        unsigned short* WtE2   = (unsigned short*)ws;              //  32768
        unsigned short* WtN2   = (unsigned short*)(ws + 32768);    // 131072
        int*            counts = (int*)(ws + 163840);              // 200000
        int*            cursor = (int*)(ws + 363840);              // 200000
        int*            partial= (int*)(ws + 563840);              //   1024
        uint2*          spak2  = (uint2*)(ws + 564864);            // 6.4e6
        unsigned int*   nodeP32= (unsigned int*)(ws + 6964864);    // 51.2e6
        float*          aggr   = (float*)(ws + 58164864);          // 25.6e6

        hipMemsetAsync(counts, 0, NN * sizeof(int), stream);
        prep_kernel4<<<NN * DD / 4 / 256, 256, 0, stream>>>(
            ei, W_f, W_s, WtE2, WtN2, counts, aggr);
        scan_part<<<NBS, 256, 0, stream>>>(counts, partial);
        scan_final2<<<NBS, 256, 0, stream>>>(counts, partial, cursor);
        scatter_kernel<<<(E_TOTAL + 255) / 256, 256, 0, stream>>>(ei, cursor, spak2);
        node_kernel3<<<(NN + MT - 1) / MT, 512, 0, stream>>>(
            x, WtN2, b_f, b_s, nodeP32);
        edge_kernel8<<<E_TOTAL / MT, 512, 0, stream>>>(
            ea, WtE2, nodeP32, aggr, spak2);
        relu_kernel4<<<6250, 256, 0, stream>>>(x, aggr, out);
    } else if (ws_size >= WS_NEED2) {
        unsigned short* WtE2   = (unsigned short*)ws;              //  32768
        unsigned short* WtN2   = (unsigned short*)(ws + 32768);    // 131072
        int*            counts = (int*)(ws + 163840);              // 200000
        int*            cursor = (int*)(ws + 363840);              // 200000
        int*            partial= (int*)(ws + 563840);              //   1024
        uint2*          spak2  = (uint2*)(ws + 564864);            // 6.4e6
        unsigned int*   nodeP32= (unsigned int*)(ws + 6964864);    // 51.2e6

        hipMemsetAsync(counts, 0, NN * sizeof(int), stream);
        prep_kernel2<<<NN * DD / 4 / 256, 256, 0, stream>>>(
            x, ei, W_f, W_s, WtE2, WtN2, counts, out);
        scan_part<<<NBS, 256, 0, stream>>>(counts, partial);
        scan_top<<<1, 256, 0, stream>>>(partial);
        scan_final<<<NBS, 256, 0, stream>>>(counts, partial, cursor);
        scatter_kernel<<<(E_TOTAL + 255) / 256, 256, 0, stream>>>(ei, cursor, spak2);
        dim3 ng((NN + MT - 1) / MT, 2);
        node_kernel2<<<ng, 256, 0, stream>>>(x, WtN2, b_f, b_s, nodeP32);
        edge_kernel2<<<E_TOTAL / MT, 512, 0, stream>>>(
            ea, WtE2, nodeP32, out, spak2);
        relu_kernel<<<6250, 256, 0, stream>>>(out);
    } else {
        unsigned short* Wt = (unsigned short*)ws;   // 163840 B
        prep_fb<<<6250, 256, 0, stream>>>(x, W_f, W_s, Wt, out);
        edge_fb<<<E_TOTAL / MT, 256, 0, stream>>>(x, ei, ea, Wt, b_f, b_s, out);
        relu_kernel<<<6250, 256, 0, stream>>>(out);
    }
}